// Round 11
// baseline (975.403 us; speedup 1.0000x reference)
//
#include <hip/hip_runtime.h>
#include <cstdint>
#include <cstddef>

// B=8, C=256/128, H=W=128. Padded NHWC bf16 tensors: [n][130][130][C], pad ring = 0.
// elem(n,h,w,c) = ((n*130 + h+1)*130 + (w+1))*C + c
// All conv weights are prepacked with BN scale FOLDED IN (w *= s[oc]); epilogues add bias only.

typedef float  f32x4 __attribute__((ext_vector_type(4)));
typedef float  f4v   __attribute__((ext_vector_type(4)));
typedef short  s16x8 __attribute__((ext_vector_type(8)));
typedef unsigned short u16x4 __attribute__((ext_vector_type(4)));

__device__ __forceinline__ float bf2f(unsigned short u) {
    unsigned x = ((unsigned)u) << 16;
    return __builtin_bit_cast(float, x);
}
__device__ __forceinline__ unsigned short f2bf(float f) {
    unsigned u = __builtin_bit_cast(unsigned, f);
    unsigned r = (u + 0x7fffu + ((u >> 16) & 1u)) >> 16;
    return (unsigned short)r;
}

#define GL_LDS(gp, lp) __builtin_amdgcn_global_load_lds( \
    (const __attribute__((address_space(1))) unsigned int*)(const void*)(gp), \
    (__attribute__((address_space(3))) unsigned int*)(void*)(lp), 16, 0, 0)

// ---------------------------------------------------------------------------
// conv3x3 + bias (+opt ReLU), bf16 MFMA implicit GEMM. m4p4, 4 blk/CU,
// 2-phase dbuf pipeline. Bijective XCD swizzle. grid ((COUT/128)*2, 64, 8)
// (used by the fallback path)
// ---------------------------------------------------------------------------
template<int CIN, int COUT, bool RELU, bool OUTF32, bool SWZ>
__global__ __launch_bounds__(256, 4)
void conv3_mfma(const unsigned short* __restrict__ in,
                const unsigned short* __restrict__ wpk,
                const float* __restrict__ bi,
                void* __restrict__ outv)
{
    __shared__ unsigned short lds[2][8704];      // 2 x 17408 B
    const int tid  = threadIdx.x;
    const int lane = tid & 63;
    const int wv   = tid >> 6;
    const int c    = lane & 15;
    const int g    = lane >> 4;

    constexpr int GX  = (COUT / 128) * 2;
    int gx, hy, n;
    if (SWZ) {
        constexpr int NWG = GX * 64 * 8;
        constexpr int Q   = NWG / 8;
        const int braw = blockIdx.x + GX * (blockIdx.y + 64 * blockIdx.z);
        const int wl   = (braw & 7) * Q + (braw >> 3);
        gx = wl % GX;
        const int rest = wl / GX;
        hy = rest & 63;
        n  = rest >> 6;
    } else {
        gx = blockIdx.x; hy = blockIdx.y; n = blockIdx.z;
    }
    const int wtile  = gx & 1;
    const int octile = gx >> 1;
    const int h0   = hy * 2;
    const int w0   = wtile * 64;
    const int r    = wv >> 1;
    const int ocbase = octile * 128 + (wv & 1) * 64;
    const int ocf0   = octile * 8 + (wv & 1) * 4;

    int addrB[3];
    #pragma unroll
    for (int kx = 0; kx < 3; ++kx) {
        int ps0 = c + kx;
        addrB[kx] = r * 4224 + ps0 * 64 + ((g ^ ((ps0 >> 1) & 3)) << 4);
    }

    int so[5];
    #pragma unroll
    for (int it = 0; it < 5; ++it) {
        int u   = it * 256 + tid;
        int row = u / 264;
        int rem = u - row * 264;
        int ps  = rem >> 2;
        int s   = rem & 3;
        int icq = s ^ ((ps >> 1) & 3);
        so[it] = ((n * 130 + h0 + row) * 130 + (w0 + ps)) * CIN + icq * 8;
    }

    auto STAGE = [&](int chunk, int bsel) {
        const unsigned short* bp = in + chunk * 32;
        char* lb = (char*)lds + bsel * 17408 + tid * 16;
        #pragma unroll
        for (int it = 0; it < 4; ++it)
            GL_LDS(bp + so[it], lb + it * 4096);
        if (wv == 0)
            GL_LDS(bp + so[4], lb + 16384);
    };

    f32x4 acc[4][4];
    #pragma unroll
    for (int m = 0; m < 4; ++m)
        #pragma unroll
        for (int p = 0; p < 4; ++p) acc[m][p] = 0.0f;

    const int NC = CIN / 32;
    STAGE(0, 0);
    __syncthreads();

    for (int chunk = 0; chunk < NC; ++chunk) {
        const int cur = chunk & 1;
        if (chunk + 1 < NC) STAGE(chunk + 1, cur ^ 1);
        const char* lb = (const char*)lds + cur * 17408;
        #pragma unroll
        for (int kk = 0; kk < 9; ++kk) {
            const int ky = kk / 3, kx = kk % 3;
            s16x8 af[4], bf[4];
            #pragma unroll
            for (int m = 0; m < 4; ++m)
                af[m] = *(const s16x8*)(wpk
                    + ((size_t)((chunk * 9 + kk) * (COUT / 16) + ocf0 + m)) * 512 + lane * 8);
            #pragma unroll
            for (int p = 0; p < 4; ++p)
                bf[p] = *(const s16x8*)(lb + addrB[kx] + ky * 4224 + p * 1024);
            #pragma unroll
            for (int m = 0; m < 4; ++m)
                #pragma unroll
                for (int p = 0; p < 4; ++p)
                    acc[m][p] = __builtin_amdgcn_mfma_f32_16x16x32_bf16(af[m], bf[p], acc[m][p], 0, 0, 0);
        }
        __syncthreads();
    }

    #pragma unroll
    for (int m = 0; m < 4; ++m) {
        const int oc4 = ocbase + m * 16 + g * 4;
        const f4v b4 = *(const f4v*)(bi + oc4);
        #pragma unroll
        for (int p = 0; p < 4; ++p) {
            const int w = w0 + p * 16 + c;
            float y[4];
            #pragma unroll
            for (int j = 0; j < 4; ++j) {
                y[j] = acc[m][p][j] + b4[j];
                if (RELU) y[j] = fmaxf(y[j], 0.0f);
            }
            if (OUTF32) {
                float* op = (float*)outv + (((size_t)n * COUT + oc4) << 14) + ((h0 + r) << 7) + w;
                op[0] = y[0]; op[16384] = y[1]; op[32768] = y[2]; op[49152] = y[3];
            } else {
                u16x4 pk;
                #pragma unroll
                for (int j = 0; j < 4; ++j) pk[j] = f2bf(y[j]);
                *(u16x4*)((unsigned short*)outv
                    + ((size_t)(n * 130 + h0 + r + 1) * 130 + w + 1) * COUT + oc4) = pk;
            }
        }
    }
}

// ---------------------------------------------------------------------------
// MERGED final convs: q=0 tlo (tl -> out 1st half), q=1 bro (pbr -> out 2nd).
// Per-q work = gx(4) x hy(64) x n(8) = 2048 blocks; TOTAL grid = 4096.
// Decode: wl = (braw&7)*512 + braw>>3 (bijective 0..4095); q=wl>>11;
//         v=wl&2047: gx=v&3, hy=(v>>2)&63, n=v>>8 (exact 3 bits).
// ---------------------------------------------------------------------------
__global__ __launch_bounds__(256, 4)
void conv3_final(const unsigned short* __restrict__ tlp,
                 const unsigned short* __restrict__ pbr,
                 const unsigned short* __restrict__ w0,   // wp_tlo; wp_bro at +589824
                 const float* __restrict__ btlo, const float* __restrict__ bbro,
                 float* __restrict__ out)
{
    __shared__ unsigned short lds[2][8704];
    const int tid  = threadIdx.x;
    const int lane = tid & 63;
    const int wv   = tid >> 6;
    const int c    = lane & 15;
    const int g    = lane >> 4;

    const int braw = blockIdx.x;                  // 0..4095
    const int wl   = (braw & 7) * 512 + (braw >> 3);
    const int q    = wl >> 11;                    // 0=tlo, 1=bro
    const int v    = wl & 2047;
    const int gx   = v & 3;
    const int hy   = (v >> 2) & 63;
    const int n    = v >> 8;                      // 0..7 exact
    const int wtile  = gx & 1;
    const int octile = gx >> 1;
    const int h0 = hy * 2;
    const int w0c = wtile * 64;
    const int r  = wv >> 1;
    const int ocbase = octile * 128 + (wv & 1) * 64;
    const int ocf0   = octile * 8 + (wv & 1) * 4;

    const unsigned short* in = q ? pbr : tlp;
    const unsigned short* wpk = w0 + (size_t)q * 589824;
    const float* bi = q ? bbro : btlo;
    float* outv = out + (size_t)q * 33554432;

    int addrB[3];
    #pragma unroll
    for (int kx = 0; kx < 3; ++kx) {
        int ps0 = c + kx;
        addrB[kx] = r * 4224 + ps0 * 64 + ((g ^ ((ps0 >> 1) & 3)) << 4);
    }

    int so[5];
    #pragma unroll
    for (int it = 0; it < 5; ++it) {
        int u   = it * 256 + tid;
        int row = u / 264;
        int rem = u - row * 264;
        int ps  = rem >> 2;
        int s   = rem & 3;
        int icq = s ^ ((ps >> 1) & 3);
        so[it] = ((n * 130 + h0 + row) * 130 + (w0c + ps)) * 256 + icq * 8;
    }

    auto STAGE = [&](int chunk, int bsel) {
        const unsigned short* bp = in + chunk * 32;
        char* lb = (char*)lds + bsel * 17408 + tid * 16;
        #pragma unroll
        for (int it = 0; it < 4; ++it)
            GL_LDS(bp + so[it], lb + it * 4096);
        if (wv == 0)
            GL_LDS(bp + so[4], lb + 16384);
    };

    f32x4 acc[4][4];
    #pragma unroll
    for (int m = 0; m < 4; ++m)
        #pragma unroll
        for (int p = 0; p < 4; ++p) acc[m][p] = 0.0f;

    STAGE(0, 0);
    __syncthreads();

    for (int chunk = 0; chunk < 8; ++chunk) {
        const int cur = chunk & 1;
        if (chunk + 1 < 8) STAGE(chunk + 1, cur ^ 1);
        const char* lb = (const char*)lds + cur * 17408;
        #pragma unroll
        for (int kk = 0; kk < 9; ++kk) {
            const int ky = kk / 3, kx = kk % 3;
            s16x8 af[4], bf[4];
            #pragma unroll
            for (int m = 0; m < 4; ++m)
                af[m] = *(const s16x8*)(wpk
                    + ((size_t)((chunk * 9 + kk) * 16 + ocf0 + m)) * 512 + lane * 8);
            #pragma unroll
            for (int p = 0; p < 4; ++p)
                bf[p] = *(const s16x8*)(lb + addrB[kx] + ky * 4224 + p * 1024);
            #pragma unroll
            for (int m = 0; m < 4; ++m)
                #pragma unroll
                for (int p = 0; p < 4; ++p)
                    acc[m][p] = __builtin_amdgcn_mfma_f32_16x16x32_bf16(af[m], bf[p], acc[m][p], 0, 0, 0);
        }
        __syncthreads();
    }

    #pragma unroll
    for (int m = 0; m < 4; ++m) {
        const int oc4 = ocbase + m * 16 + g * 4;
        const f4v b4 = *(const f4v*)(bi + oc4);
        #pragma unroll
        for (int p = 0; p < 4; ++p) {
            const int w = w0c + p * 16 + c;
            float* op = outv + (((size_t)n * 256 + oc4) << 14) + ((h0 + r) << 7) + w;
            op[0]     = fmaxf(acc[m][p][0] + b4[0], 0.0f);
            op[16384] = fmaxf(acc[m][p][1] + b4[1], 0.0f);
            op[32768] = fmaxf(acc[m][p][2] + b4[2], 0.0f);
            op[49152] = fmaxf(acc[m][p][3] + b4[3], 0.0f);
        }
    }
}

// ---------------------------------------------------------------------------
// MERGED stage-A: t,l,b,r in ONE dispatch, XCD-grouped. T5 setprio A/B here.
// grid (4096)
// ---------------------------------------------------------------------------
__global__ __launch_bounds__(256, 4)
void conv3_tlbr(const unsigned short* __restrict__ in,
                const unsigned short* __restrict__ wq0,
                const float* __restrict__ bA,
                unsigned short* __restrict__ tt0)
{
    __shared__ unsigned short lds[2][8704];
    const int tid  = threadIdx.x;
    const int lane = tid & 63;
    const int wv   = tid >> 6;
    const int c    = lane & 15;
    const int g    = lane >> 4;

    const int b  = blockIdx.x;
    const int x  = b & 7;
    const int t  = b >> 3;
    const int q  = t & 3;
    const int ts = x + 8 * (t >> 2);
    const int wtile = ts & 1;
    const int hy    = (ts >> 1) & 63;
    const int n     = ts >> 7;
    const int h0 = hy * 2;
    const int w0 = wtile * 64;
    const int r  = wv >> 1;
    const int ocbase = (wv & 1) * 64;
    const int ocf0   = (wv & 1) * 4;

    const unsigned short* wpk = wq0 + q * 294912;
    const int outoff = ((q & 1) << 1) | (q >> 1);          // 0,2,1,3
    unsigned short* outv = tt0 + (size_t)outoff * ((size_t)8 * 130 * 130 * 128);
    const float* bi = bA + q * 128;

    int addrB[3];
    #pragma unroll
    for (int kx = 0; kx < 3; ++kx) {
        int ps0 = c + kx;
        addrB[kx] = r * 4224 + ps0 * 64 + ((g ^ ((ps0 >> 1) & 3)) << 4);
    }

    int so[5];
    #pragma unroll
    for (int it = 0; it < 5; ++it) {
        int u   = it * 256 + tid;
        int row = u / 264;
        int rem = u - row * 264;
        int ps  = rem >> 2;
        int s   = rem & 3;
        int icq = s ^ ((ps >> 1) & 3);
        so[it] = ((n * 130 + h0 + row) * 130 + (w0 + ps)) * 256 + icq * 8;
    }

    auto STAGE = [&](int chunk, int bsel) {
        const unsigned short* bp = in + chunk * 32;
        char* lb = (char*)lds + bsel * 17408 + tid * 16;
        #pragma unroll
        for (int it = 0; it < 4; ++it)
            GL_LDS(bp + so[it], lb + it * 4096);
        if (wv == 0)
            GL_LDS(bp + so[4], lb + 16384);
    };

    f32x4 acc[4][4];
    #pragma unroll
    for (int m = 0; m < 4; ++m)
        #pragma unroll
        for (int p = 0; p < 4; ++p) acc[m][p] = 0.0f;

    STAGE(0, 0);
    __syncthreads();

    for (int chunk = 0; chunk < 8; ++chunk) {
        const int cur = chunk & 1;
        if (chunk + 1 < 8) STAGE(chunk + 1, cur ^ 1);
        const char* lb = (const char*)lds + cur * 17408;
        __builtin_amdgcn_s_setprio(1);               // T5: favor MFMA-entering wave
        #pragma unroll
        for (int kk = 0; kk < 9; ++kk) {
            const int ky = kk / 3, kx = kk % 3;
            s16x8 af[4], bf[4];
            #pragma unroll
            for (int m = 0; m < 4; ++m)
                af[m] = *(const s16x8*)(wpk
                    + ((size_t)((chunk * 9 + kk) * 8 + ocf0 + m)) * 512 + lane * 8);
            #pragma unroll
            for (int p = 0; p < 4; ++p)
                bf[p] = *(const s16x8*)(lb + addrB[kx] + ky * 4224 + p * 1024);
            #pragma unroll
            for (int m = 0; m < 4; ++m)
                #pragma unroll
                for (int p = 0; p < 4; ++p)
                    acc[m][p] = __builtin_amdgcn_mfma_f32_16x16x32_bf16(af[m], bf[p], acc[m][p], 0, 0, 0);
        }
        __builtin_amdgcn_s_setprio(0);
        __syncthreads();
    }

    #pragma unroll
    for (int m = 0; m < 4; ++m) {
        const int oc4 = ocbase + m * 16 + g * 4;
        const f4v b4 = *(const f4v*)(bi + oc4);
        #pragma unroll
        for (int p = 0; p < 4; ++p) {
            const int w = w0 + p * 16 + c;
            u16x4 pk;
            #pragma unroll
            for (int j = 0; j < 4; ++j)
                pk[j] = f2bf(fmaxf(acc[m][p][j] + b4[j], 0.0f));
            *(u16x4*)(outv + ((size_t)(n * 130 + h0 + r + 1) * 130 + w + 1) * 128 + oc4) = pk;
        }
    }
}

// ---------------------------------------------------------------------------
// FUSED chain head, tl & br merged (round-9 proven). grid (4096)
// ---------------------------------------------------------------------------
__global__ __launch_bounds__(256, 4)
void conv3p1_k(const unsigned short* __restrict__ u0,    // tt; bb at +T128
               const unsigned short* __restrict__ xb,
               const unsigned short* __restrict__ w30,   // wp_tl3; wp_br3 at +294912
               const unsigned short* __restrict__ w10,   // wp_tl1; wp_br1 at +65536
               const float* __restrict__ bsum0,          // [0..255]=tl, [256..511]=br
               unsigned short* __restrict__ outTL,
               unsigned short* __restrict__ outBR)
{
    __shared__ unsigned short lds[2][8704];
    const int tid  = threadIdx.x;
    const int lane = tid & 63;
    const int wv   = tid >> 6;
    const int c    = lane & 15;
    const int g    = lane >> 4;

    const int b  = blockIdx.x;
    const int x  = b & 7;
    const int s  = b >> 3;
    const int q  = s & 1;
    const int gx = (s >> 1) & 3;
    const int sp = x + 8 * (s >> 3);
    const int hy = sp & 63;
    const int n  = sp >> 6;
    const int wtile  = gx & 1;
    const int octile = gx >> 1;
    const int h0 = hy * 2;
    const int w0 = wtile * 64;
    const int r  = wv >> 1;
    const int ocbase = octile * 128 + (wv & 1) * 64;
    const int ocf0   = octile * 8 + (wv & 1) * 4;

    const unsigned short* in3 = u0 + (size_t)q * ((size_t)8 * 130 * 130 * 128);
    const unsigned short* w3  = w30 + q * 294912;
    const unsigned short* w1  = w10 + q * 65536;
    const float* bi = bsum0 + q * 256;
    unsigned short* outv = q ? outBR : outTL;

    int addrB[3];
    #pragma unroll
    for (int kx = 0; kx < 3; ++kx) {
        int ps0 = c + kx;
        addrB[kx] = r * 4224 + ps0 * 64 + ((g ^ ((ps0 >> 1) & 3)) << 4);
    }
    const int addrC1 = r * 4096 + c * 64 + ((g ^ ((c >> 1) & 3)) << 4);

    int so3[5];
    #pragma unroll
    for (int it = 0; it < 5; ++it) {
        int u   = it * 256 + tid;
        int row = u / 264;
        int rem = u - row * 264;
        int ps  = rem >> 2;
        int ss  = rem & 3;
        int icq = ss ^ ((ps >> 1) & 3);
        so3[it] = ((n * 130 + h0 + row) * 130 + (w0 + ps)) * 128 + icq * 8;
    }
    int so1[4];
    #pragma unroll
    for (int it = 0; it < 4; ++it) {
        int u   = it * 256 + tid;
        int sub = u >> 9;
        int v   = u & 511;
        int row = v >> 8;
        int rem = v & 255;
        int px  = rem >> 2;
        int ss  = rem & 3;
        int icq = ss ^ ((px >> 1) & 3);
        so1[it] = ((n * 130 + h0 + 1 + row) * 130 + (w0 + px + 1)) * 256 + sub * 32 + icq * 8;
    }

    auto STAGE3 = [&](int chunk, int bsel) {
        const unsigned short* bp = in3 + chunk * 32;
        char* lb = (char*)lds + bsel * 17408 + tid * 16;
        #pragma unroll
        for (int it = 0; it < 4; ++it)
            GL_LDS(bp + so3[it], lb + it * 4096);
        if (wv == 0)
            GL_LDS(bp + so3[4], lb + 16384);
    };
    auto STAGE1 = [&](int j, int bsel) {
        const unsigned short* bp = xb + j * 64;
        char* lb = (char*)lds + bsel * 17408 + tid * 16;
        #pragma unroll
        for (int it = 0; it < 4; ++it)
            GL_LDS(bp + so1[it], lb + it * 4096);
    };

    f32x4 acc[4][4];
    #pragma unroll
    for (int m = 0; m < 4; ++m)
        #pragma unroll
        for (int p = 0; p < 4; ++p) acc[m][p] = 0.0f;

    STAGE3(0, 0);
    __syncthreads();

    for (int ph = 0; ph < 8; ++ph) {
        const int cur = ph & 1;
        if (ph < 3)      STAGE3(ph + 1, cur ^ 1);
        else if (ph < 7) STAGE1(ph - 3, cur ^ 1);
        const char* lb = (const char*)lds + cur * 17408;
        if (ph < 4) {
            #pragma unroll
            for (int kk = 0; kk < 9; ++kk) {
                const int ky = kk / 3, kx = kk % 3;
                s16x8 af[4], bf[4];
                #pragma unroll
                for (int m = 0; m < 4; ++m)
                    af[m] = *(const s16x8*)(w3
                        + ((size_t)((ph * 9 + kk) * 16 + ocf0 + m)) * 512 + lane * 8);
                #pragma unroll
                for (int p = 0; p < 4; ++p)
                    bf[p] = *(const s16x8*)(lb + addrB[kx] + ky * 4224 + p * 1024);
                #pragma unroll
                for (int m = 0; m < 4; ++m)
                    #pragma unroll
                    for (int p = 0; p < 4; ++p)
                        acc[m][p] = __builtin_amdgcn_mfma_f32_16x16x32_bf16(af[m], bf[p], acc[m][p], 0, 0, 0);
            }
        } else {
            const int j = ph - 4;
            #pragma unroll
            for (int sub = 0; sub < 2; ++sub) {
                s16x8 af[4], bf[4];
                #pragma unroll
                for (int m = 0; m < 4; ++m)
                    af[m] = *(const s16x8*)(w1
                        + ((size_t)(((j * 2 + sub) * 16) + ocf0 + m)) * 512 + lane * 8);
                #pragma unroll
                for (int p = 0; p < 4; ++p)
                    bf[p] = *(const s16x8*)(lb + sub * 8192 + addrC1 + p * 1024);
                #pragma unroll
                for (int m = 0; m < 4; ++m)
                    #pragma unroll
                    for (int p = 0; p < 4; ++p)
                        acc[m][p] = __builtin_amdgcn_mfma_f32_16x16x32_bf16(af[m], bf[p], acc[m][p], 0, 0, 0);
            }
        }
        __syncthreads();
    }

    #pragma unroll
    for (int m = 0; m < 4; ++m) {
        const int oc4 = ocbase + m * 16 + g * 4;
        const f4v b4 = *(const f4v*)(bi + oc4);
        #pragma unroll
        for (int p = 0; p < 4; ++p) {
            const int w = w0 + p * 16 + c;
            u16x4 pk;
            #pragma unroll
            for (int j = 0; j < 4; ++j)
                pk[j] = f2bf(fmaxf(acc[m][p][j] + b4[j], 0.0f));
            *(u16x4*)(outv + ((size_t)(n * 130 + h0 + r + 1) * 130 + w + 1) * 256 + oc4) = pk;
        }
    }
}

// ---------------------------------------------------------------------------
__global__ __launch_bounds__(128)
void pool_h2_k(unsigned short* __restrict__ ta, unsigned short* __restrict__ tb)
{
    const int sel = blockIdx.x & 1;
    const int col = blockIdx.x >> 1;
    unsigned short* p = sel ? tb : ta;
    const int n = col >> 7, w = col & 127, cth = threadIdx.x;
    unsigned short* base = p + (((size_t)n * 130 + 1) * 130 + (w + 1)) * 128 + cth;
    const int stride = 130 * 128;
    float m = -3.402823466e+38f;
    if (sel == 0) {
        for (int gq = 0; gq < 16; ++gq) {
            const int h0 = 127 - gq * 8;
            float v[8];
            #pragma unroll
            for (int j = 0; j < 8; ++j) v[j] = bf2f(base[(size_t)(h0 - j) * stride]);
            unsigned short o[8];
            #pragma unroll
            for (int j = 0; j < 8; ++j) { m = fmaxf(m, v[j]); o[j] = f2bf(m); }
            #pragma unroll
            for (int j = 0; j < 8; ++j) base[(size_t)(h0 - j) * stride] = o[j];
        }
    } else {
        for (int gq = 0; gq < 16; ++gq) {
            const int h0 = gq * 8;
            float v[8];
            #pragma unroll
            for (int j = 0; j < 8; ++j) v[j] = bf2f(base[(size_t)(h0 + j) * stride]);
            unsigned short o[8];
            #pragma unroll
            for (int j = 0; j < 8; ++j) { m = fmaxf(m, v[j]); o[j] = f2bf(m); }
            #pragma unroll
            for (int j = 0; j < 8; ++j) base[(size_t)(h0 + j) * stride] = o[j];
        }
    }
}

__global__ __launch_bounds__(128)
void pool_w_add2_k(const unsigned short* __restrict__ la, unsigned short* __restrict__ ta,
                   const unsigned short* __restrict__ lb, unsigned short* __restrict__ tb)
{
    const int sel = blockIdx.x & 1;
    const int row = blockIdx.x >> 1;
    const unsigned short* ls = sel ? lb : la;
    unsigned short* td = sel ? tb : ta;
    const int n = row >> 7, hh = row & 127, cth = threadIdx.x;
    const size_t rowbase = ((size_t)(n * 130 + hh + 1) * 130) * 128 + cth;
    float m = -3.402823466e+38f;
    if (sel == 0) {
        for (int gq = 0; gq < 16; ++gq) {
            const int w0 = 127 - gq * 8;
            float lv[8], tv[8];
            #pragma unroll
            for (int j = 0; j < 8; ++j) {
                size_t off = rowbase + (size_t)(w0 - j + 1) * 128;
                lv[j] = bf2f(ls[off]); tv[j] = bf2f(td[off]);
            }
            unsigned short o[8];
            #pragma unroll
            for (int j = 0; j < 8; ++j) { m = fmaxf(m, lv[j]); o[j] = f2bf(m + tv[j]); }
            #pragma unroll
            for (int j = 0; j < 8; ++j) td[rowbase + (size_t)(w0 - j + 1) * 128] = o[j];
        }
    } else {
        for (int gq = 0; gq < 16; ++gq) {
            const int w0 = gq * 8;
            float lv[8], tv[8];
            #pragma unroll
            for (int j = 0; j < 8; ++j) {
                size_t off = rowbase + (size_t)(w0 + j + 1) * 128;
                lv[j] = bf2f(ls[off]); tv[j] = bf2f(td[off]);
            }
            unsigned short o[8];
            #pragma unroll
            for (int j = 0; j < 8; ++j) { m = fmaxf(m, lv[j]); o[j] = f2bf(m + tv[j]); }
            #pragma unroll
            for (int j = 0; j < 8; ++j) td[rowbase + (size_t)(w0 + j + 1) * 128] = o[j];
        }
    }
}

// ---------------------------------------------------------------------------
__global__ __launch_bounds__(256)
void padzero_k(unsigned short* __restrict__ t, int C)
{
    int idx = blockIdx.x * 256 + threadIdx.x;
    int n = blockIdx.y;
    int cpu = C >> 3;
    if (idx >= 516 * cpu) return;
    int cell = idx / cpu, cq = idx - cell * cpu;
    int h, w;
    if (cell < 260) { h = (cell < 130) ? -1 : 128; w = (cell % 130) - 1; }
    else { int j = cell - 260; w = (j < 128) ? -1 : 128; h = j & 127; }
    size_t off = (((size_t)n * 130 + h + 1) * 130 + (w + 1)) * C + cq * 8;
    uint4 z; z.x = 0; z.y = 0; z.z = 0; z.w = 0;
    *(uint4*)(t + off) = z;
}

__global__ __launch_bounds__(256)
void padzero_all_k(unsigned short* xb, unsigned short* tt, unsigned short* bb,
                   unsigned short* ll, unsigned short* rr, unsigned short* pbr)
{
    const int id = blockIdx.y;
    unsigned short* t = id == 0 ? xb : (id == 1 ? tt : (id == 2 ? bb :
                        (id == 3 ? ll : (id == 4 ? rr : pbr))));
    const int C = (id == 0 || id == 5) ? 256 : 128;
    int idx = blockIdx.x * 256 + threadIdx.x;
    int n = blockIdx.z;
    int cpu = C >> 3;
    if (idx >= 516 * cpu) return;
    int cell = idx / cpu, cq = idx - cell * cpu;
    int h, w;
    if (cell < 260) { h = (cell < 130) ? -1 : 128; w = (cell % 130) - 1; }
    else { int j = cell - 260; w = (j < 128) ? -1 : 128; h = j & 127; }
    size_t off = (((size_t)n * 130 + h + 1) * 130 + (w + 1)) * C + cq * 8;
    uint4 z; z.x = 0; z.y = 0; z.z = 0; z.w = 0;
    *(uint4*)(t + off) = z;
}

// ---------------------------------------------------------------------------
__global__ __launch_bounds__(256)
void transform_x_k(const float* __restrict__ x, unsigned short* __restrict__ xb)
{
    __shared__ float sm[64][132];
    const int h = blockIdx.x, n = blockIdx.y, t = threadIdx.x;
    for (int cc0 = 0; cc0 < 256; cc0 += 64) {
        __syncthreads();
        {
            int ci = t >> 7, wi = t & 127;
            #pragma unroll 8
            for (int k = 0; k < 32; ++k)
                sm[ci + 2 * k][wi] = x[((size_t)(n * 256 + cc0 + ci + 2 * k) << 14) + (h << 7) + wi];
        }
        __syncthreads();
        {
            int wi = t >> 1, cq = t & 1;
            unsigned short tmp[32];
            #pragma unroll
            for (int m2 = 0; m2 < 32; ++m2) tmp[m2] = f2bf(sm[cq * 32 + m2][wi]);
            unsigned short* dst = xb + (((size_t)n * 130 + h + 1) * 130 + wi + 1) * 256 + cc0 + cq * 32;
            #pragma unroll
            for (int q = 0; q < 4; ++q) *(uint4*)(dst + q * 8) = *(const uint4*)(tmp + q * 8);
        }
    }
}

// ---------------------------------------------------------------------------
struct PrepArgs {
    const float* w[10];          // t,l,b,r,tl3,br3,tlo,bro,tl1,br1
    unsigned short* dst[10];
    const float* s[10];
    const float* bv[4];
    const float* bx[4];          // b_tl3,b_tl1,b_br3,b_br1
    float* bA; float* bsum;
};

__global__ __launch_bounds__(256)
void prepack_all_k(PrepArgs a)
{
    const int id = blockIdx.y;
    int idx = blockIdx.x * 256 + threadIdx.x;
    if (id == 10) {
        if (idx < 512) a.bA[idx] = a.bv[idx >> 7][idx & 127];
        else if (idx < 768)  { int i = idx - 512; a.bsum[i]       = a.bx[0][i] + a.bx[1][i]; }
        else if (idx < 1024) { int i = idx - 768; a.bsum[256 + i] = a.bx[2][i] + a.bx[3][i]; }
        return;
    }
    if (id >= 8) {
        if (idx >= 65536) return;
        int ic = idx & 255, oc = idx >> 8;
        float v = a.w[id][oc * 256 + ic] * a.s[id][oc];
        int chunk = ic >> 5, icr = ic & 31, gg = icr >> 3, j = icr & 7;
        int m = oc >> 4, ocr = oc & 15, ln = gg * 16 + ocr;
        a.dst[id][((size_t)(chunk * 16 + m)) * 512 + ln * 8 + j] = f2bf(v);
        return;
    }
    const int CIN  = (id < 4) ? 256 : ((id < 6) ? 128 : 256);
    const int COUT = (id < 4) ? 128 : 256;
    if (idx >= COUT * CIN * 9) return;
    int kk = idx % 9; int rest = idx / 9;
    int ic = rest % CIN; int oc = rest / CIN;
    float v = a.w[id][(size_t)(oc * CIN + ic) * 9 + kk] * a.s[id][oc];
    int chunk = ic >> 5, icr = ic & 31, gg = icr >> 3, j = icr & 7;
    int m = oc >> 4, ocr = oc & 15, ln = gg * 16 + ocr;
    a.dst[id][((size_t)((chunk * 9 + kk) * (COUT / 16) + m)) * 512 + ln * 8 + j] = f2bf(v);
}

// ---------------------------------------------------------------------------
extern "C" void kernel_launch(void* const* d_in, const int* in_sizes, int n_in,
                              void* d_out, int out_size, void* d_ws, size_t ws_size,
                              hipStream_t stream)
{
    const float* x     = (const float*)d_in[0];
    const float* w_t   = (const float*)d_in[1];
    const float* s_t   = (const float*)d_in[2];
    const float* b_t   = (const float*)d_in[3];
    const float* w_l   = (const float*)d_in[4];
    const float* s_l   = (const float*)d_in[5];
    const float* b_l   = (const float*)d_in[6];
    const float* w_b   = (const float*)d_in[7];
    const float* s_b   = (const float*)d_in[8];
    const float* b_b   = (const float*)d_in[9];
    const float* w_r   = (const float*)d_in[10];
    const float* s_r   = (const float*)d_in[11];
    const float* b_r   = (const float*)d_in[12];
    const float* w_tl3 = (const float*)d_in[13];
    const float* s_tl3 = (const float*)d_in[14];
    const float* b_tl3 = (const float*)d_in[15];
    const float* w_br3 = (const float*)d_in[16];
    const float* s_br3 = (const float*)d_in[17];
    const float* b_br3 = (const float*)d_in[18];
    const float* w_tl1 = (const float*)d_in[19];
    const float* s_tl1 = (const float*)d_in[20];
    const float* b_tl1 = (const float*)d_in[21];
    const float* w_br1 = (const float*)d_in[22];
    const float* s_br1 = (const float*)d_in[23];
    const float* b_br1 = (const float*)d_in[24];
    const float* w_tlo = (const float*)d_in[25];
    const float* s_tlo = (const float*)d_in[26];
    const float* b_tlo = (const float*)d_in[27];
    const float* w_bro = (const float*)d_in[28];
    const float* s_bro = (const float*)d_in[29];
    const float* b_bro = (const float*)d_in[30];

    typedef unsigned short ush;
    const size_t T256 = (size_t)8 * 130 * 130 * 256;
    const size_t T128 = (size_t)8 * 130 * 130 * 128;

    ush* xb = (ush*)d_ws;
    ush* tt = xb + T256;
    ush* bb = tt + T128;
    ush* ll = bb + T128;
    ush* rr = ll + T128;
    ush* wq = rr + T128;
    ush* wp_t   = wq;                    // stage-A 4x 294912 contiguous
    ush* wp_l   = wp_t   + 294912;
    ush* wp_b   = wp_l   + 294912;
    ush* wp_r   = wp_b   + 294912;
    ush* wp_tl3 = wp_r   + 294912;       // tl3, br3 contiguous
    ush* wp_br3 = wp_tl3 + 294912;
    ush* wp_tlo = wp_br3 + 294912;       // tlo, bro contiguous
    ush* wp_bro = wp_tlo + 589824;
    ush* wp_tl1 = wp_bro + 589824;       // tl1, br1 contiguous
    ush* wp_br1 = wp_tl1 + 65536;
    float* bA   = (float*)(wp_br1 + 65536);  // 512 f
    float* bsum = bA + 512;                  // 512 f
    ush* end_fixed = (ush*)(bsum + 512);
    ush* tl  = ll;                           // 256-ch buffer over ll+rr

    // P_br placement: own ws buffer if it fits, else d_out 1st half (serialized)
    const size_t used  = (size_t)(end_fixed - xb);           // ush units
    const bool roomy = ws_size >= (used + T256) * 2 + 1024;
    ush* pbr = roomy ? end_fixed : (ush*)d_out;

    PrepArgs pa;
    pa.w[0] = w_t;  pa.w[1] = w_l;  pa.w[2] = w_b;  pa.w[3] = w_r;
    pa.w[4] = w_tl3; pa.w[5] = w_br3; pa.w[6] = w_tlo; pa.w[7] = w_bro;
    pa.w[8] = w_tl1; pa.w[9] = w_br1;
    pa.dst[0] = wp_t;  pa.dst[1] = wp_l;  pa.dst[2] = wp_b;  pa.dst[3] = wp_r;
    pa.dst[4] = wp_tl3; pa.dst[5] = wp_br3; pa.dst[6] = wp_tlo; pa.dst[7] = wp_bro;
    pa.dst[8] = wp_tl1; pa.dst[9] = wp_br1;
    pa.s[0] = s_t;  pa.s[1] = s_l;  pa.s[2] = s_b;  pa.s[3] = s_r;
    pa.s[4] = s_tl3; pa.s[5] = s_br3; pa.s[6] = s_tlo; pa.s[7] = s_bro;
    pa.s[8] = s_tl1; pa.s[9] = s_br1;
    pa.bv[0] = b_t; pa.bv[1] = b_l; pa.bv[2] = b_b; pa.bv[3] = b_r;
    pa.bx[0] = b_tl3; pa.bx[1] = b_tl1; pa.bx[2] = b_br3; pa.bx[3] = b_br1;
    pa.bA = bA; pa.bsum = bsum;
    prepack_all_k<<<dim3(2304, 11), dim3(256), 0, stream>>>(pa);
    padzero_all_k<<<dim3(516, 6, 8), dim3(256), 0, stream>>>(xb, tt, bb, ll, rr, pbr);
    transform_x_k<<<dim3(128, 8), dim3(256), 0, stream>>>(x, xb);

    // stage A: t,l,b,r merged, XCD-tile-grouped (+ T5 setprio A/B)
    conv3_tlbr<<<dim3(4096), dim3(256), 0, stream>>>(xb, wp_t, bA, tt);

    // pools
    pool_h2_k<<<dim3(2048), dim3(128), 0, stream>>>(tt, bb);
    pool_w_add2_k<<<dim3(2048), dim3(128), 0, stream>>>(ll, tt, rr, bb);

    // fused chain heads: tl -> tl buffer, br -> pbr
    padzero_k<<<dim3(66, 8), dim3(256), 0, stream>>>(tl, 256);
    conv3p1_k<<<dim3(4096), dim3(256), 0, stream>>>(tt, xb, wp_tl3, wp_tl1, bsum, tl, pbr);

    if (roomy) {
        // merged final convs: tlo+bro in one dispatch (disjoint d_out halves)
        conv3_final<<<dim3(4096), dim3(256), 0, stream>>>(tl, pbr, wp_tlo, b_tlo, b_bro,
                                                          (float*)d_out);
    } else {
        // serialized fallback: bro reads pbr (= d_out 1st half) first
        conv3_mfma<256, 256, true, true, true><<<dim3(4, 64, 8), dim3(256), 0, stream>>>(
            pbr, wp_bro, b_bro, (float*)d_out + 33554432);
        conv3_mfma<256, 256, true, true, true><<<dim3(4, 64, 8), dim3(256), 0, stream>>>(
            tl, wp_tlo, b_tlo, d_out);
    }
}

// Round 12
// 915.004 us; speedup vs baseline: 1.0660x; 1.0660x over previous
//
#include <hip/hip_runtime.h>
#include <cstdint>
#include <cstddef>

// B=8, C=256/128, H=W=128. Padded NHWC bf16 tensors: [n][130][130][C], pad ring = 0.
// elem(n,h,w,c) = ((n*130 + h+1)*130 + (w+1))*C + c
// All conv weights are prepacked with BN scale FOLDED IN (w *= s[oc]); epilogues add bias only.
// conv3_tlbr uses 32x32x16 MFMA (A/B experiment); all other convs use 16x16x32.

typedef float  f32x4  __attribute__((ext_vector_type(4)));
typedef float  f32x16 __attribute__((ext_vector_type(16)));
typedef float  f4v    __attribute__((ext_vector_type(4)));
typedef short  s16x8  __attribute__((ext_vector_type(8)));
typedef unsigned short u16x4 __attribute__((ext_vector_type(4)));

__device__ __forceinline__ float bf2f(unsigned short u) {
    unsigned x = ((unsigned)u) << 16;
    return __builtin_bit_cast(float, x);
}
__device__ __forceinline__ unsigned short f2bf(float f) {
    unsigned u = __builtin_bit_cast(unsigned, f);
    unsigned r = (u + 0x7fffu + ((u >> 16) & 1u)) >> 16;
    return (unsigned short)r;
}

#define GL_LDS(gp, lp) __builtin_amdgcn_global_load_lds( \
    (const __attribute__((address_space(1))) unsigned int*)(const void*)(gp), \
    (__attribute__((address_space(3))) unsigned int*)(void*)(lp), 16, 0, 0)

// ---------------------------------------------------------------------------
// conv3x3 + bias (+opt ReLU), 16x16x32 MFMA. m4p4, 4 blk/CU, 2-phase dbuf.
// Bijective XCD swizzle. grid ((COUT/128)*2, 64, 8)
// ---------------------------------------------------------------------------
template<int CIN, int COUT, bool RELU, bool OUTF32, bool SWZ>
__global__ __launch_bounds__(256, 4)
void conv3_mfma(const unsigned short* __restrict__ in,
                const unsigned short* __restrict__ wpk,
                const float* __restrict__ bi,
                void* __restrict__ outv)
{
    __shared__ unsigned short lds[2][8704];      // 2 x 17408 B
    const int tid  = threadIdx.x;
    const int lane = tid & 63;
    const int wv   = tid >> 6;
    const int c    = lane & 15;
    const int g    = lane >> 4;

    constexpr int GX  = (COUT / 128) * 2;
    int gx, hy, n;
    if (SWZ) {
        constexpr int NWG = GX * 64 * 8;
        constexpr int Q   = NWG / 8;
        const int braw = blockIdx.x + GX * (blockIdx.y + 64 * blockIdx.z);
        const int wl   = (braw & 7) * Q + (braw >> 3);
        gx = wl % GX;
        const int rest = wl / GX;
        hy = rest & 63;
        n  = rest >> 6;
    } else {
        gx = blockIdx.x; hy = blockIdx.y; n = blockIdx.z;
    }
    const int wtile  = gx & 1;
    const int octile = gx >> 1;
    const int h0   = hy * 2;
    const int w0   = wtile * 64;
    const int r    = wv >> 1;
    const int ocbase = octile * 128 + (wv & 1) * 64;
    const int ocf0   = octile * 8 + (wv & 1) * 4;

    int addrB[3];
    #pragma unroll
    for (int kx = 0; kx < 3; ++kx) {
        int ps0 = c + kx;
        addrB[kx] = r * 4224 + ps0 * 64 + ((g ^ ((ps0 >> 1) & 3)) << 4);
    }

    int so[5];
    #pragma unroll
    for (int it = 0; it < 5; ++it) {
        int u   = it * 256 + tid;
        int row = u / 264;
        int rem = u - row * 264;
        int ps  = rem >> 2;
        int s   = rem & 3;
        int icq = s ^ ((ps >> 1) & 3);
        so[it] = ((n * 130 + h0 + row) * 130 + (w0 + ps)) * CIN + icq * 8;
    }

    auto STAGE = [&](int chunk, int bsel) {
        const unsigned short* bp = in + chunk * 32;
        char* lb = (char*)lds + bsel * 17408 + tid * 16;
        #pragma unroll
        for (int it = 0; it < 4; ++it)
            GL_LDS(bp + so[it], lb + it * 4096);
        if (wv == 0)
            GL_LDS(bp + so[4], lb + 16384);
    };

    f32x4 acc[4][4];
    #pragma unroll
    for (int m = 0; m < 4; ++m)
        #pragma unroll
        for (int p = 0; p < 4; ++p) acc[m][p] = 0.0f;

    const int NC = CIN / 32;
    STAGE(0, 0);
    __syncthreads();

    for (int chunk = 0; chunk < NC; ++chunk) {
        const int cur = chunk & 1;
        if (chunk + 1 < NC) STAGE(chunk + 1, cur ^ 1);
        const char* lb = (const char*)lds + cur * 17408;
        #pragma unroll
        for (int kk = 0; kk < 9; ++kk) {
            const int ky = kk / 3, kx = kk % 3;
            s16x8 af[4], bf[4];
            #pragma unroll
            for (int m = 0; m < 4; ++m)
                af[m] = *(const s16x8*)(wpk
                    + ((size_t)((chunk * 9 + kk) * (COUT / 16) + ocf0 + m)) * 512 + lane * 8);
            #pragma unroll
            for (int p = 0; p < 4; ++p)
                bf[p] = *(const s16x8*)(lb + addrB[kx] + ky * 4224 + p * 1024);
            #pragma unroll
            for (int m = 0; m < 4; ++m)
                #pragma unroll
                for (int p = 0; p < 4; ++p)
                    acc[m][p] = __builtin_amdgcn_mfma_f32_16x16x32_bf16(af[m], bf[p], acc[m][p], 0, 0, 0);
        }
        __syncthreads();
    }

    #pragma unroll
    for (int m = 0; m < 4; ++m) {
        const int oc4 = ocbase + m * 16 + g * 4;
        const f4v b4 = *(const f4v*)(bi + oc4);
        #pragma unroll
        for (int p = 0; p < 4; ++p) {
            const int w = w0 + p * 16 + c;
            float y[4];
            #pragma unroll
            for (int j = 0; j < 4; ++j) {
                y[j] = acc[m][p][j] + b4[j];
                if (RELU) y[j] = fmaxf(y[j], 0.0f);
            }
            if (OUTF32) {
                float* op = (float*)outv + (((size_t)n * COUT + oc4) << 14) + ((h0 + r) << 7) + w;
                op[0] = y[0]; op[16384] = y[1]; op[32768] = y[2]; op[49152] = y[3];
            } else {
                u16x4 pk;
                #pragma unroll
                for (int j = 0; j < 4; ++j) pk[j] = f2bf(y[j]);
                *(u16x4*)((unsigned short*)outv
                    + ((size_t)(n * 130 + h0 + r + 1) * 130 + w + 1) * COUT + oc4) = pk;
            }
        }
    }
}

// ---------------------------------------------------------------------------
// MERGED stage-A: t,l,b,r in ONE dispatch, XCD-grouped — 32x32x16 MFMA variant.
// Wave (r, och): 1 row x 64 px x 64 oc = 2x2 fragments of 32x32.
// B-frag: n32 = lane&31 = px, kg = lane>>5; k = ks*16 + kg*8 + j.
// LDS layout + staging + swizzle involution UNCHANGED from 16x16 version.
// C/D: col = lane&31 = px, row = (reg&3) + 8*(reg>>2) + 4*kg = oc.
// grid (4096)
// ---------------------------------------------------------------------------
__global__ __launch_bounds__(256, 4)
void conv3_tlbr(const unsigned short* __restrict__ in,
                const unsigned short* __restrict__ wq0,
                const float* __restrict__ bA,
                unsigned short* __restrict__ tt0)
{
    __shared__ unsigned short lds[2][8704];
    const int tid  = threadIdx.x;
    const int lane = tid & 63;
    const int wv   = tid >> 6;
    const int n32  = lane & 31;
    const int kg   = lane >> 5;

    const int b  = blockIdx.x;
    const int x  = b & 7;
    const int t  = b >> 3;
    const int q  = t & 3;
    const int ts = x + 8 * (t >> 2);
    const int wtile = ts & 1;
    const int hy    = (ts >> 1) & 63;
    const int n     = ts >> 7;
    const int h0 = hy * 2;
    const int w0 = wtile * 64;
    const int r  = wv >> 1;
    const int och = wv & 1;
    const int ocbase = och * 64;

    const unsigned short* wpk = wq0 + q * 294912;
    const int outoff = ((q & 1) << 1) | (q >> 1);          // 0,2,1,3
    unsigned short* outv = tt0 + (size_t)outoff * ((size_t)8 * 130 * 130 * 128);
    const float* bi = bA + q * 128;

    // B-read bases: ps = n32 + kx (+p*32, which doesn't affect the swizzle:
    // (32>>1)&3 == 0), slot = (ks*2+kg) ^ ((ps>>1)&3)
    int abase[3], swzk[3];
    #pragma unroll
    for (int kx = 0; kx < 3; ++kx) {
        int ps0 = n32 + kx;
        abase[kx] = r * 4224 + ps0 * 64;
        swzk[kx]  = (ps0 >> 1) & 3;
    }

    int so[5];
    #pragma unroll
    for (int it = 0; it < 5; ++it) {
        int u   = it * 256 + tid;
        int row = u / 264;
        int rem = u - row * 264;
        int ps  = rem >> 2;
        int s   = rem & 3;
        int icq = s ^ ((ps >> 1) & 3);
        so[it] = ((n * 130 + h0 + row) * 130 + (w0 + ps)) * 256 + icq * 8;
    }

    auto STAGE = [&](int chunk, int bsel) {
        const unsigned short* bp = in + chunk * 32;
        char* lb = (char*)lds + bsel * 17408 + tid * 16;
        #pragma unroll
        for (int it = 0; it < 4; ++it)
            GL_LDS(bp + so[it], lb + it * 4096);
        if (wv == 0)
            GL_LDS(bp + so[4], lb + 16384);
    };

    f32x16 acc[2][2];
    #pragma unroll
    for (int m = 0; m < 2; ++m)
        #pragma unroll
        for (int p = 0; p < 2; ++p) acc[m][p] = 0.0f;

    STAGE(0, 0);
    __syncthreads();

    for (int chunk = 0; chunk < 8; ++chunk) {
        const int cur = chunk & 1;
        if (chunk + 1 < 8) STAGE(chunk + 1, cur ^ 1);
        const char* lb = (const char*)lds + cur * 17408;
        #pragma unroll
        for (int kk = 0; kk < 9; ++kk) {
            const int ky = kk / 3, kx = kk % 3;
            s16x8 af[2][2], bf[2][2];          // [m or p][ks]
            #pragma unroll
            for (int ks = 0; ks < 2; ++ks) {
                #pragma unroll
                for (int m = 0; m < 2; ++m)
                    af[m][ks] = *(const s16x8*)(wpk
                        + ((size_t)((((chunk * 9 + kk) * 2 + ks) * 4) + och * 2 + m)) * 512
                        + lane * 8);
                #pragma unroll
                for (int p = 0; p < 2; ++p)
                    bf[p][ks] = *(const s16x8*)(lb + abase[kx] + ky * 4224 + p * 2048
                        + (((ks * 2 + kg) ^ swzk[kx]) << 4));
            }
            #pragma unroll
            for (int ks = 0; ks < 2; ++ks)
                #pragma unroll
                for (int m = 0; m < 2; ++m)
                    #pragma unroll
                    for (int p = 0; p < 2; ++p)
                        acc[m][p] = __builtin_amdgcn_mfma_f32_32x32x16_bf16(
                            af[m][ks], bf[p][ks], acc[m][p], 0, 0, 0);
        }
        __syncthreads();
    }

    // epilogue: reg group q4 (regs q4*4+j) -> oc rows 8*q4 + 4*kg + j
    #pragma unroll
    for (int m = 0; m < 2; ++m) {
        #pragma unroll
        for (int p = 0; p < 2; ++p) {
            const int w = w0 + p * 32 + n32;
            const size_t pxoff = ((size_t)(n * 130 + h0 + r + 1) * 130 + w + 1) * 128;
            #pragma unroll
            for (int q4 = 0; q4 < 4; ++q4) {
                const int ocr = ocbase + m * 32 + q4 * 8 + kg * 4;
                const f4v b4 = *(const f4v*)(bi + ocr);
                u16x4 pk;
                #pragma unroll
                for (int j = 0; j < 4; ++j)
                    pk[j] = f2bf(fmaxf(acc[m][p][q4 * 4 + j] + b4[j], 0.0f));
                *(u16x4*)(outv + pxoff + ocr) = pk;
            }
        }
    }
}

// ---------------------------------------------------------------------------
// FUSED chain head, tl & br merged (round-9 proven, 16x16). grid (4096)
// ---------------------------------------------------------------------------
__global__ __launch_bounds__(256, 4)
void conv3p1_k(const unsigned short* __restrict__ u0,    // tt; bb at +T128
               const unsigned short* __restrict__ xb,
               const unsigned short* __restrict__ w30,   // wp_tl3; wp_br3 at +294912
               const unsigned short* __restrict__ w10,   // wp_tl1; wp_br1 at +65536
               const float* __restrict__ bsum0,          // [0..255]=tl, [256..511]=br
               unsigned short* __restrict__ outTL,
               unsigned short* __restrict__ outBR)
{
    __shared__ unsigned short lds[2][8704];
    const int tid  = threadIdx.x;
    const int lane = tid & 63;
    const int wv   = tid >> 6;
    const int c    = lane & 15;
    const int g    = lane >> 4;

    const int b  = blockIdx.x;
    const int x  = b & 7;
    const int s  = b >> 3;
    const int q  = s & 1;
    const int gx = (s >> 1) & 3;
    const int sp = x + 8 * (s >> 3);
    const int hy = sp & 63;
    const int n  = sp >> 6;
    const int wtile  = gx & 1;
    const int octile = gx >> 1;
    const int h0 = hy * 2;
    const int w0 = wtile * 64;
    const int r  = wv >> 1;
    const int ocbase = octile * 128 + (wv & 1) * 64;
    const int ocf0   = octile * 8 + (wv & 1) * 4;

    const unsigned short* in3 = u0 + (size_t)q * ((size_t)8 * 130 * 130 * 128);
    const unsigned short* w3  = w30 + q * 294912;
    const unsigned short* w1  = w10 + q * 65536;
    const float* bi = bsum0 + q * 256;
    unsigned short* outv = q ? outBR : outTL;

    int addrB[3];
    #pragma unroll
    for (int kx = 0; kx < 3; ++kx) {
        int ps0 = c + kx;
        addrB[kx] = r * 4224 + ps0 * 64 + ((g ^ ((ps0 >> 1) & 3)) << 4);
    }
    const int addrC1 = r * 4096 + c * 64 + ((g ^ ((c >> 1) & 3)) << 4);

    int so3[5];
    #pragma unroll
    for (int it = 0; it < 5; ++it) {
        int u   = it * 256 + tid;
        int row = u / 264;
        int rem = u - row * 264;
        int ps  = rem >> 2;
        int ss  = rem & 3;
        int icq = ss ^ ((ps >> 1) & 3);
        so3[it] = ((n * 130 + h0 + row) * 130 + (w0 + ps)) * 128 + icq * 8;
    }
    int so1[4];
    #pragma unroll
    for (int it = 0; it < 4; ++it) {
        int u   = it * 256 + tid;
        int sub = u >> 9;
        int v   = u & 511;
        int row = v >> 8;
        int rem = v & 255;
        int px  = rem >> 2;
        int ss  = rem & 3;
        int icq = ss ^ ((px >> 1) & 3);
        so1[it] = ((n * 130 + h0 + 1 + row) * 130 + (w0 + px + 1)) * 256 + sub * 32 + icq * 8;
    }

    auto STAGE3 = [&](int chunk, int bsel) {
        const unsigned short* bp = in3 + chunk * 32;
        char* lb = (char*)lds + bsel * 17408 + tid * 16;
        #pragma unroll
        for (int it = 0; it < 4; ++it)
            GL_LDS(bp + so3[it], lb + it * 4096);
        if (wv == 0)
            GL_LDS(bp + so3[4], lb + 16384);
    };
    auto STAGE1 = [&](int j, int bsel) {
        const unsigned short* bp = xb + j * 64;
        char* lb = (char*)lds + bsel * 17408 + tid * 16;
        #pragma unroll
        for (int it = 0; it < 4; ++it)
            GL_LDS(bp + so1[it], lb + it * 4096);
    };

    f32x4 acc[4][4];
    #pragma unroll
    for (int m = 0; m < 4; ++m)
        #pragma unroll
        for (int p = 0; p < 4; ++p) acc[m][p] = 0.0f;

    STAGE3(0, 0);
    __syncthreads();

    for (int ph = 0; ph < 8; ++ph) {
        const int cur = ph & 1;
        if (ph < 3)      STAGE3(ph + 1, cur ^ 1);
        else if (ph < 7) STAGE1(ph - 3, cur ^ 1);
        const char* lb = (const char*)lds + cur * 17408;
        if (ph < 4) {
            #pragma unroll
            for (int kk = 0; kk < 9; ++kk) {
                const int ky = kk / 3, kx = kk % 3;
                s16x8 af[4], bf[4];
                #pragma unroll
                for (int m = 0; m < 4; ++m)
                    af[m] = *(const s16x8*)(w3
                        + ((size_t)((ph * 9 + kk) * 16 + ocf0 + m)) * 512 + lane * 8);
                #pragma unroll
                for (int p = 0; p < 4; ++p)
                    bf[p] = *(const s16x8*)(lb + addrB[kx] + ky * 4224 + p * 1024);
                #pragma unroll
                for (int m = 0; m < 4; ++m)
                    #pragma unroll
                    for (int p = 0; p < 4; ++p)
                        acc[m][p] = __builtin_amdgcn_mfma_f32_16x16x32_bf16(af[m], bf[p], acc[m][p], 0, 0, 0);
            }
        } else {
            const int j = ph - 4;
            #pragma unroll
            for (int sub = 0; sub < 2; ++sub) {
                s16x8 af[4], bf[4];
                #pragma unroll
                for (int m = 0; m < 4; ++m)
                    af[m] = *(const s16x8*)(w1
                        + ((size_t)(((j * 2 + sub) * 16) + ocf0 + m)) * 512 + lane * 8);
                #pragma unroll
                for (int p = 0; p < 4; ++p)
                    bf[p] = *(const s16x8*)(lb + sub * 8192 + addrC1 + p * 1024);
                #pragma unroll
                for (int m = 0; m < 4; ++m)
                    #pragma unroll
                    for (int p = 0; p < 4; ++p)
                        acc[m][p] = __builtin_amdgcn_mfma_f32_16x16x32_bf16(af[m], bf[p], acc[m][p], 0, 0, 0);
            }
        }
        __syncthreads();
    }

    #pragma unroll
    for (int m = 0; m < 4; ++m) {
        const int oc4 = ocbase + m * 16 + g * 4;
        const f4v b4 = *(const f4v*)(bi + oc4);
        #pragma unroll
        for (int p = 0; p < 4; ++p) {
            const int w = w0 + p * 16 + c;
            u16x4 pk;
            #pragma unroll
            for (int j = 0; j < 4; ++j)
                pk[j] = f2bf(fmaxf(acc[m][p][j] + b4[j], 0.0f));
            *(u16x4*)(outv + ((size_t)(n * 130 + h0 + r + 1) * 130 + w + 1) * 256 + oc4) = pk;
        }
    }
}

// ---------------------------------------------------------------------------
__global__ __launch_bounds__(128)
void pool_h2_k(unsigned short* __restrict__ ta, unsigned short* __restrict__ tb)
{
    const int sel = blockIdx.x & 1;
    const int col = blockIdx.x >> 1;
    unsigned short* p = sel ? tb : ta;
    const int n = col >> 7, w = col & 127, cth = threadIdx.x;
    unsigned short* base = p + (((size_t)n * 130 + 1) * 130 + (w + 1)) * 128 + cth;
    const int stride = 130 * 128;
    float m = -3.402823466e+38f;
    if (sel == 0) {
        for (int gq = 0; gq < 16; ++gq) {
            const int h0 = 127 - gq * 8;
            float v[8];
            #pragma unroll
            for (int j = 0; j < 8; ++j) v[j] = bf2f(base[(size_t)(h0 - j) * stride]);
            unsigned short o[8];
            #pragma unroll
            for (int j = 0; j < 8; ++j) { m = fmaxf(m, v[j]); o[j] = f2bf(m); }
            #pragma unroll
            for (int j = 0; j < 8; ++j) base[(size_t)(h0 - j) * stride] = o[j];
        }
    } else {
        for (int gq = 0; gq < 16; ++gq) {
            const int h0 = gq * 8;
            float v[8];
            #pragma unroll
            for (int j = 0; j < 8; ++j) v[j] = bf2f(base[(size_t)(h0 + j) * stride]);
            unsigned short o[8];
            #pragma unroll
            for (int j = 0; j < 8; ++j) { m = fmaxf(m, v[j]); o[j] = f2bf(m); }
            #pragma unroll
            for (int j = 0; j < 8; ++j) base[(size_t)(h0 + j) * stride] = o[j];
        }
    }
}

__global__ __launch_bounds__(128)
void pool_w_add2_k(const unsigned short* __restrict__ la, unsigned short* __restrict__ ta,
                   const unsigned short* __restrict__ lb, unsigned short* __restrict__ tb)
{
    const int sel = blockIdx.x & 1;
    const int row = blockIdx.x >> 1;
    const unsigned short* ls = sel ? lb : la;
    unsigned short* td = sel ? tb : ta;
    const int n = row >> 7, hh = row & 127, cth = threadIdx.x;
    const size_t rowbase = ((size_t)(n * 130 + hh + 1) * 130) * 128 + cth;
    float m = -3.402823466e+38f;
    if (sel == 0) {
        for (int gq = 0; gq < 16; ++gq) {
            const int w0 = 127 - gq * 8;
            float lv[8], tv[8];
            #pragma unroll
            for (int j = 0; j < 8; ++j) {
                size_t off = rowbase + (size_t)(w0 - j + 1) * 128;
                lv[j] = bf2f(ls[off]); tv[j] = bf2f(td[off]);
            }
            unsigned short o[8];
            #pragma unroll
            for (int j = 0; j < 8; ++j) { m = fmaxf(m, lv[j]); o[j] = f2bf(m + tv[j]); }
            #pragma unroll
            for (int j = 0; j < 8; ++j) td[rowbase + (size_t)(w0 - j + 1) * 128] = o[j];
        }
    } else {
        for (int gq = 0; gq < 16; ++gq) {
            const int w0 = gq * 8;
            float lv[8], tv[8];
            #pragma unroll
            for (int j = 0; j < 8; ++j) {
                size_t off = rowbase + (size_t)(w0 + j + 1) * 128;
                lv[j] = bf2f(ls[off]); tv[j] = bf2f(td[off]);
            }
            unsigned short o[8];
            #pragma unroll
            for (int j = 0; j < 8; ++j) { m = fmaxf(m, lv[j]); o[j] = f2bf(m + tv[j]); }
            #pragma unroll
            for (int j = 0; j < 8; ++j) td[rowbase + (size_t)(w0 + j + 1) * 128] = o[j];
        }
    }
}

// ---------------------------------------------------------------------------
__global__ __launch_bounds__(256)
void padzero_k(unsigned short* __restrict__ t, int C)
{
    int idx = blockIdx.x * 256 + threadIdx.x;
    int n = blockIdx.y;
    int cpu = C >> 3;
    if (idx >= 516 * cpu) return;
    int cell = idx / cpu, cq = idx - cell * cpu;
    int h, w;
    if (cell < 260) { h = (cell < 130) ? -1 : 128; w = (cell % 130) - 1; }
    else { int j = cell - 260; w = (j < 128) ? -1 : 128; h = j & 127; }
    size_t off = (((size_t)n * 130 + h + 1) * 130 + (w + 1)) * C + cq * 8;
    uint4 z; z.x = 0; z.y = 0; z.z = 0; z.w = 0;
    *(uint4*)(t + off) = z;
}

__global__ __launch_bounds__(256)
void padzero_all_k(unsigned short* xb, unsigned short* tt, unsigned short* bb,
                   unsigned short* ll, unsigned short* rr, unsigned short* pbr)
{
    const int id = blockIdx.y;
    unsigned short* t = id == 0 ? xb : (id == 1 ? tt : (id == 2 ? bb :
                        (id == 3 ? ll : (id == 4 ? rr : pbr))));
    const int C = (id == 0 || id == 5) ? 256 : 128;
    int idx = blockIdx.x * 256 + threadIdx.x;
    int n = blockIdx.z;
    int cpu = C >> 3;
    if (idx >= 516 * cpu) return;
    int cell = idx / cpu, cq = idx - cell * cpu;
    int h, w;
    if (cell < 260) { h = (cell < 130) ? -1 : 128; w = (cell % 130) - 1; }
    else { int j = cell - 260; w = (j < 128) ? -1 : 128; h = j & 127; }
    size_t off = (((size_t)n * 130 + h + 1) * 130 + (w + 1)) * C + cq * 8;
    uint4 z; z.x = 0; z.y = 0; z.z = 0; z.w = 0;
    *(uint4*)(t + off) = z;
}

// ---------------------------------------------------------------------------
__global__ __launch_bounds__(256)
void transform_x_k(const float* __restrict__ x, unsigned short* __restrict__ xb)
{
    __shared__ float sm[64][132];
    const int h = blockIdx.x, n = blockIdx.y, t = threadIdx.x;
    for (int cc0 = 0; cc0 < 256; cc0 += 64) {
        __syncthreads();
        {
            int ci = t >> 7, wi = t & 127;
            #pragma unroll 8
            for (int k = 0; k < 32; ++k)
                sm[ci + 2 * k][wi] = x[((size_t)(n * 256 + cc0 + ci + 2 * k) << 14) + (h << 7) + wi];
        }
        __syncthreads();
        {
            int wi = t >> 1, cq = t & 1;
            unsigned short tmp[32];
            #pragma unroll
            for (int m2 = 0; m2 < 32; ++m2) tmp[m2] = f2bf(sm[cq * 32 + m2][wi]);
            unsigned short* dst = xb + (((size_t)n * 130 + h + 1) * 130 + wi + 1) * 256 + cc0 + cq * 32;
            #pragma unroll
            for (int q = 0; q < 4; ++q) *(uint4*)(dst + q * 8) = *(const uint4*)(tmp + q * 8);
        }
    }
}

// ---------------------------------------------------------------------------
// merged prepack. ids 0-3 (stage A) pack 32x32x16 fragments; ids 4-7 conv3
// 16x16x32; ids 8-9 conv1 16x16x32; id 10 bias concats. Scale folded into w.
// grid (2304, 11)
// ---------------------------------------------------------------------------
struct PrepArgs {
    const float* w[10];          // t,l,b,r,tl3,br3,tlo,bro,tl1,br1
    unsigned short* dst[10];
    const float* s[10];
    const float* bv[4];
    const float* bx[4];          // b_tl3,b_tl1,b_br3,b_br1
    float* bA; float* bsum;
};

__global__ __launch_bounds__(256)
void prepack_all_k(PrepArgs a)
{
    const int id = blockIdx.y;
    int idx = blockIdx.x * 256 + threadIdx.x;
    if (id == 10) {
        if (idx < 512) a.bA[idx] = a.bv[idx >> 7][idx & 127];
        else if (idx < 768)  { int i = idx - 512; a.bsum[i]       = a.bx[0][i] + a.bx[1][i]; }
        else if (idx < 1024) { int i = idx - 768; a.bsum[256 + i] = a.bx[2][i] + a.bx[3][i]; }
        return;
    }
    if (id >= 8) {
        if (idx >= 65536) return;
        int ic = idx & 255, oc = idx >> 8;
        float v = a.w[id][oc * 256 + ic] * a.s[id][oc];
        int chunk = ic >> 5, icr = ic & 31, gg = icr >> 3, j = icr & 7;
        int m = oc >> 4, ocr = oc & 15, ln = gg * 16 + ocr;
        a.dst[id][((size_t)(chunk * 16 + m)) * 512 + ln * 8 + j] = f2bf(v);
        return;
    }
    if (id < 4) {
        // 32x32x16 packing: CIN=256, COUT=128.
        // frag = ((chunk*9+kk)*2 + ks)*4 + oc>>5 ; lane = kg*32 + (oc&31) ; elem j
        if (idx >= 294912) return;
        int kk = idx % 9; int rest = idx / 9;
        int ic = rest % 256; int oc = rest / 256;
        float v = a.w[id][(size_t)(oc * 256 + ic) * 9 + kk] * a.s[id][oc];
        int chunk = ic >> 5, icl = ic & 31;
        int ks = icl >> 4, k16 = icl & 15, kg = k16 >> 3, j = k16 & 7;
        int ln = kg * 32 + (oc & 31);
        int f  = ((chunk * 9 + kk) * 2 + ks) * 4 + (oc >> 5);
        a.dst[id][(size_t)f * 512 + ln * 8 + j] = f2bf(v);
        return;
    }
    // ids 4-7: 16x16x32 conv3 packing
    const int CIN  = (id < 6) ? 128 : 256;
    const int COUT = 256;
    if (idx >= COUT * CIN * 9) return;
    int kk = idx % 9; int rest = idx / 9;
    int ic = rest % CIN; int oc = rest / CIN;
    float v = a.w[id][(size_t)(oc * CIN + ic) * 9 + kk] * a.s[id][oc];
    int chunk = ic >> 5, icr = ic & 31, gg = icr >> 3, j = icr & 7;
    int m = oc >> 4, ocr = oc & 15, ln = gg * 16 + ocr;
    a.dst[id][((size_t)((chunk * 9 + kk) * (COUT / 16) + m)) * 512 + ln * 8 + j] = f2bf(v);
}

// ---------------------------------------------------------------------------
extern "C" void kernel_launch(void* const* d_in, const int* in_sizes, int n_in,
                              void* d_out, int out_size, void* d_ws, size_t ws_size,
                              hipStream_t stream)
{
    const float* x     = (const float*)d_in[0];
    const float* w_t   = (const float*)d_in[1];
    const float* s_t   = (const float*)d_in[2];
    const float* b_t   = (const float*)d_in[3];
    const float* w_l   = (const float*)d_in[4];
    const float* s_l   = (const float*)d_in[5];
    const float* b_l   = (const float*)d_in[6];
    const float* w_b   = (const float*)d_in[7];
    const float* s_b   = (const float*)d_in[8];
    const float* b_b   = (const float*)d_in[9];
    const float* w_r   = (const float*)d_in[10];
    const float* s_r   = (const float*)d_in[11];
    const float* b_r   = (const float*)d_in[12];
    const float* w_tl3 = (const float*)d_in[13];
    const float* s_tl3 = (const float*)d_in[14];
    const float* b_tl3 = (const float*)d_in[15];
    const float* w_br3 = (const float*)d_in[16];
    const float* s_br3 = (const float*)d_in[17];
    const float* b_br3 = (const float*)d_in[18];
    const float* w_tl1 = (const float*)d_in[19];
    const float* s_tl1 = (const float*)d_in[20];
    const float* b_tl1 = (const float*)d_in[21];
    const float* w_br1 = (const float*)d_in[22];
    const float* s_br1 = (const float*)d_in[23];
    const float* b_br1 = (const float*)d_in[24];
    const float* w_tlo = (const float*)d_in[25];
    const float* s_tlo = (const float*)d_in[26];
    const float* b_tlo = (const float*)d_in[27];
    const float* w_bro = (const float*)d_in[28];
    const float* s_bro = (const float*)d_in[29];
    const float* b_bro = (const float*)d_in[30];

    typedef unsigned short ush;
    const size_t T256 = (size_t)8 * 130 * 130 * 256;
    const size_t T128 = (size_t)8 * 130 * 130 * 128;

    ush* xb = (ush*)d_ws;
    ush* tt = xb + T256;
    ush* bb = tt + T128;
    ush* ll = bb + T128;
    ush* rr = ll + T128;
    ush* wq = rr + T128;
    ush* wp_t   = wq;                    // stage-A 4x 294912 contiguous (32x32 packed)
    ush* wp_l   = wp_t   + 294912;
    ush* wp_b   = wp_l   + 294912;
    ush* wp_r   = wp_b   + 294912;
    ush* wp_tl3 = wp_r   + 294912;       // tl3, br3 contiguous (16x16)
    ush* wp_br3 = wp_tl3 + 294912;
    ush* wp_tlo = wp_br3 + 294912;       // tlo, bro contiguous (16x16)
    ush* wp_bro = wp_tlo + 589824;
    ush* wp_tl1 = wp_bro + 589824;       // tl1, br1 contiguous (16x16)
    ush* wp_br1 = wp_tl1 + 65536;
    float* bA   = (float*)(wp_br1 + 65536);  // 512 f
    float* bsum = bA + 512;                  // 512 f
    ush* tl  = ll;                           // 256-ch buffer over ll+rr
    ush* pbr = (ush*)d_out;                  // P_br staging in d_out 1st half (round-9 proven)

    PrepArgs pa;
    pa.w[0] = w_t;  pa.w[1] = w_l;  pa.w[2] = w_b;  pa.w[3] = w_r;
    pa.w[4] = w_tl3; pa.w[5] = w_br3; pa.w[6] = w_tlo; pa.w[7] = w_bro;
    pa.w[8] = w_tl1; pa.w[9] = w_br1;
    pa.dst[0] = wp_t;  pa.dst[1] = wp_l;  pa.dst[2] = wp_b;  pa.dst[3] = wp_r;
    pa.dst[4] = wp_tl3; pa.dst[5] = wp_br3; pa.dst[6] = wp_tlo; pa.dst[7] = wp_bro;
    pa.dst[8] = wp_tl1; pa.dst[9] = wp_br1;
    pa.s[0] = s_t;  pa.s[1] = s_l;  pa.s[2] = s_b;  pa.s[3] = s_r;
    pa.s[4] = s_tl3; pa.s[5] = s_br3; pa.s[6] = s_tlo; pa.s[7] = s_bro;
    pa.s[8] = s_tl1; pa.s[9] = s_br1;
    pa.bv[0] = b_t; pa.bv[1] = b_l; pa.bv[2] = b_b; pa.bv[3] = b_r;
    pa.bx[0] = b_tl3; pa.bx[1] = b_tl1; pa.bx[2] = b_br3; pa.bx[3] = b_br1;
    pa.bA = bA; pa.bsum = bsum;
    prepack_all_k<<<dim3(2304, 11), dim3(256), 0, stream>>>(pa);
    padzero_all_k<<<dim3(516, 6, 8), dim3(256), 0, stream>>>(xb, tt, bb, ll, rr, pbr);
    transform_x_k<<<dim3(128, 8), dim3(256), 0, stream>>>(x, xb);

    // stage A: t,l,b,r merged, XCD-tile-grouped — 32x32 MFMA experiment
    conv3_tlbr<<<dim3(4096), dim3(256), 0, stream>>>(xb, wp_t, bA, tt);

    // pools
    pool_h2_k<<<dim3(2048), dim3(128), 0, stream>>>(tt, bb);
    pool_w_add2_k<<<dim3(2048), dim3(128), 0, stream>>>(ll, tt, rr, bb);

    // fused chain heads: tl -> tl buffer, br -> d_out 1st half (P_br)
    padzero_k<<<dim3(66, 8), dim3(256), 0, stream>>>(tl, 256);
    conv3p1_k<<<dim3(4096), dim3(256), 0, stream>>>(tt, xb, wp_tl3, wp_tl1, bsum, tl, pbr);

    // serialized finals (round-9 proven): bro reads P_br (d_out 1st half) and
    // writes 2nd half; then tlo overwrites 1st half.
    conv3_mfma<256, 256, true, true, true><<<dim3(4, 64, 8), dim3(256), 0, stream>>>(
        pbr, wp_bro, b_bro, (float*)d_out + 33554432);
    conv3_mfma<256, 256, true, true, true><<<dim3(4, 64, 8), dim3(256), 0, stream>>>(
        tl, wp_tlo, b_tlo, d_out);
}

// Round 13
// 864.770 us; speedup vs baseline: 1.1279x; 1.0581x over previous
//
#include <hip/hip_runtime.h>
#include <cstdint>
#include <cstddef>

// B=8, C=256/128, H=W=128. Padded NHWC bf16 tensors: [n][130][130][C], pad ring = 0.
// elem(n,h,w,c) = ((n*130 + h+1)*130 + (w+1))*C + c
// All conv weights are prepacked with BN scale FOLDED IN (w *= s[oc]); epilogues add bias only.

typedef float  f32x4 __attribute__((ext_vector_type(4)));
typedef float  f4v   __attribute__((ext_vector_type(4)));
typedef short  s16x8 __attribute__((ext_vector_type(8)));
typedef unsigned short u16x4 __attribute__((ext_vector_type(4)));

__device__ __forceinline__ float bf2f(unsigned short u) {
    unsigned x = ((unsigned)u) << 16;
    return __builtin_bit_cast(float, x);
}
__device__ __forceinline__ unsigned short f2bf(float f) {
    unsigned u = __builtin_bit_cast(unsigned, f);
    unsigned r = (u + 0x7fffu + ((u >> 16) & 1u)) >> 16;
    return (unsigned short)r;
}

#define GL_LDS(gp, lp) __builtin_amdgcn_global_load_lds( \
    (const __attribute__((address_space(1))) unsigned int*)(const void*)(gp), \
    (__attribute__((address_space(3))) unsigned int*)(void*)(lp), 16, 0, 0)

// ---------------------------------------------------------------------------
// conv3x3 + bias (+opt ReLU), 16x16x32 MFMA. m4p4, 4 blk/CU, 2-phase dbuf.
// Bijective XCD swizzle. grid ((COUT/128)*2, 64, 8)
// ---------------------------------------------------------------------------
template<int CIN, int COUT, bool RELU, bool OUTF32, bool SWZ>
__global__ __launch_bounds__(256, 4)
void conv3_mfma(const unsigned short* __restrict__ in,
                const unsigned short* __restrict__ wpk,
                const float* __restrict__ bi,
                void* __restrict__ outv)
{
    __shared__ unsigned short lds[2][8704];      // 2 x 17408 B
    const int tid  = threadIdx.x;
    const int lane = tid & 63;
    const int wv   = tid >> 6;
    const int c    = lane & 15;
    const int g    = lane >> 4;

    constexpr int GX  = (COUT / 128) * 2;
    int gx, hy, n;
    if (SWZ) {
        constexpr int NWG = GX * 64 * 8;
        constexpr int Q   = NWG / 8;
        const int braw = blockIdx.x + GX * (blockIdx.y + 64 * blockIdx.z);
        const int wl   = (braw & 7) * Q + (braw >> 3);
        gx = wl % GX;
        const int rest = wl / GX;
        hy = rest & 63;
        n  = rest >> 6;
    } else {
        gx = blockIdx.x; hy = blockIdx.y; n = blockIdx.z;
    }
    const int wtile  = gx & 1;
    const int octile = gx >> 1;
    const int h0   = hy * 2;
    const int w0   = wtile * 64;
    const int r    = wv >> 1;
    const int ocbase = octile * 128 + (wv & 1) * 64;
    const int ocf0   = octile * 8 + (wv & 1) * 4;

    int addrB[3];
    #pragma unroll
    for (int kx = 0; kx < 3; ++kx) {
        int ps0 = c + kx;
        addrB[kx] = r * 4224 + ps0 * 64 + ((g ^ ((ps0 >> 1) & 3)) << 4);
    }

    int so[5];
    #pragma unroll
    for (int it = 0; it < 5; ++it) {
        int u   = it * 256 + tid;
        int row = u / 264;
        int rem = u - row * 264;
        int ps  = rem >> 2;
        int s   = rem & 3;
        int icq = s ^ ((ps >> 1) & 3);
        so[it] = ((n * 130 + h0 + row) * 130 + (w0 + ps)) * CIN + icq * 8;
    }

    auto STAGE = [&](int chunk, int bsel) {
        const unsigned short* bp = in + chunk * 32;
        char* lb = (char*)lds + bsel * 17408 + tid * 16;
        #pragma unroll
        for (int it = 0; it < 4; ++it)
            GL_LDS(bp + so[it], lb + it * 4096);
        if (wv == 0)
            GL_LDS(bp + so[4], lb + 16384);
    };

    f32x4 acc[4][4];
    #pragma unroll
    for (int m = 0; m < 4; ++m)
        #pragma unroll
        for (int p = 0; p < 4; ++p) acc[m][p] = 0.0f;

    const int NC = CIN / 32;
    STAGE(0, 0);
    __syncthreads();

    for (int chunk = 0; chunk < NC; ++chunk) {
        const int cur = chunk & 1;
        if (chunk + 1 < NC) STAGE(chunk + 1, cur ^ 1);
        const char* lb = (const char*)lds + cur * 17408;
        #pragma unroll
        for (int kk = 0; kk < 9; ++kk) {
            const int ky = kk / 3, kx = kk % 3;
            s16x8 af[4], bf[4];
            #pragma unroll
            for (int m = 0; m < 4; ++m)
                af[m] = *(const s16x8*)(wpk
                    + ((size_t)((chunk * 9 + kk) * (COUT / 16) + ocf0 + m)) * 512 + lane * 8);
            #pragma unroll
            for (int p = 0; p < 4; ++p)
                bf[p] = *(const s16x8*)(lb + addrB[kx] + ky * 4224 + p * 1024);
            #pragma unroll
            for (int m = 0; m < 4; ++m)
                #pragma unroll
                for (int p = 0; p < 4; ++p)
                    acc[m][p] = __builtin_amdgcn_mfma_f32_16x16x32_bf16(af[m], bf[p], acc[m][p], 0, 0, 0);
        }
        __syncthreads();
    }

    #pragma unroll
    for (int m = 0; m < 4; ++m) {
        const int oc4 = ocbase + m * 16 + g * 4;
        const f4v b4 = *(const f4v*)(bi + oc4);
        #pragma unroll
        for (int p = 0; p < 4; ++p) {
            const int w = w0 + p * 16 + c;
            float y[4];
            #pragma unroll
            for (int j = 0; j < 4; ++j) {
                y[j] = acc[m][p][j] + b4[j];
                if (RELU) y[j] = fmaxf(y[j], 0.0f);
            }
            if (OUTF32) {
                float* op = (float*)outv + (((size_t)n * COUT + oc4) << 14) + ((h0 + r) << 7) + w;
                op[0] = y[0]; op[16384] = y[1]; op[32768] = y[2]; op[49152] = y[3];
            } else {
                u16x4 pk;
                #pragma unroll
                for (int j = 0; j < 4; ++j) pk[j] = f2bf(y[j]);
                *(u16x4*)((unsigned short*)outv
                    + ((size_t)(n * 130 + h0 + r + 1) * 130 + w + 1) * COUT + oc4) = pk;
            }
        }
    }
}

// ---------------------------------------------------------------------------
// MERGED stage-A: t,l,b,r in ONE dispatch, XCD-grouped (round-9 proven, 266us).
// grid (4096)
// ---------------------------------------------------------------------------
__global__ __launch_bounds__(256, 4)
void conv3_tlbr(const unsigned short* __restrict__ in,
                const unsigned short* __restrict__ wq0,
                const float* __restrict__ bA,
                unsigned short* __restrict__ tt0)
{
    __shared__ unsigned short lds[2][8704];
    const int tid  = threadIdx.x;
    const int lane = tid & 63;
    const int wv   = tid >> 6;
    const int c    = lane & 15;
    const int g    = lane >> 4;

    const int b  = blockIdx.x;
    const int x  = b & 7;
    const int t  = b >> 3;
    const int q  = t & 3;
    const int ts = x + 8 * (t >> 2);
    const int wtile = ts & 1;
    const int hy    = (ts >> 1) & 63;
    const int n     = ts >> 7;
    const int h0 = hy * 2;
    const int w0 = wtile * 64;
    const int r  = wv >> 1;
    const int ocbase = (wv & 1) * 64;
    const int ocf0   = (wv & 1) * 4;

    const unsigned short* wpk = wq0 + q * 294912;
    const int outoff = ((q & 1) << 1) | (q >> 1);          // 0,2,1,3
    unsigned short* outv = tt0 + (size_t)outoff * ((size_t)8 * 130 * 130 * 128);
    const float* bi = bA + q * 128;

    int addrB[3];
    #pragma unroll
    for (int kx = 0; kx < 3; ++kx) {
        int ps0 = c + kx;
        addrB[kx] = r * 4224 + ps0 * 64 + ((g ^ ((ps0 >> 1) & 3)) << 4);
    }

    int so[5];
    #pragma unroll
    for (int it = 0; it < 5; ++it) {
        int u   = it * 256 + tid;
        int row = u / 264;
        int rem = u - row * 264;
        int ps  = rem >> 2;
        int s   = rem & 3;
        int icq = s ^ ((ps >> 1) & 3);
        so[it] = ((n * 130 + h0 + row) * 130 + (w0 + ps)) * 256 + icq * 8;
    }

    auto STAGE = [&](int chunk, int bsel) {
        const unsigned short* bp = in + chunk * 32;
        char* lb = (char*)lds + bsel * 17408 + tid * 16;
        #pragma unroll
        for (int it = 0; it < 4; ++it)
            GL_LDS(bp + so[it], lb + it * 4096);
        if (wv == 0)
            GL_LDS(bp + so[4], lb + 16384);
    };

    f32x4 acc[4][4];
    #pragma unroll
    for (int m = 0; m < 4; ++m)
        #pragma unroll
        for (int p = 0; p < 4; ++p) acc[m][p] = 0.0f;

    STAGE(0, 0);
    __syncthreads();

    for (int chunk = 0; chunk < 8; ++chunk) {
        const int cur = chunk & 1;
        if (chunk + 1 < 8) STAGE(chunk + 1, cur ^ 1);
        const char* lb = (const char*)lds + cur * 17408;
        #pragma unroll
        for (int kk = 0; kk < 9; ++kk) {
            const int ky = kk / 3, kx = kk % 3;
            s16x8 af[4], bf[4];
            #pragma unroll
            for (int m = 0; m < 4; ++m)
                af[m] = *(const s16x8*)(wpk
                    + ((size_t)((chunk * 9 + kk) * 8 + ocf0 + m)) * 512 + lane * 8);
            #pragma unroll
            for (int p = 0; p < 4; ++p)
                bf[p] = *(const s16x8*)(lb + addrB[kx] + ky * 4224 + p * 1024);
            #pragma unroll
            for (int m = 0; m < 4; ++m)
                #pragma unroll
                for (int p = 0; p < 4; ++p)
                    acc[m][p] = __builtin_amdgcn_mfma_f32_16x16x32_bf16(af[m], bf[p], acc[m][p], 0, 0, 0);
        }
        __syncthreads();
    }

    #pragma unroll
    for (int m = 0; m < 4; ++m) {
        const int oc4 = ocbase + m * 16 + g * 4;
        const f4v b4 = *(const f4v*)(bi + oc4);
        #pragma unroll
        for (int p = 0; p < 4; ++p) {
            const int w = w0 + p * 16 + c;
            u16x4 pk;
            #pragma unroll
            for (int j = 0; j < 4; ++j)
                pk[j] = f2bf(fmaxf(acc[m][p][j] + b4[j], 0.0f));
            *(u16x4*)(outv + ((size_t)(n * 130 + h0 + r + 1) * 130 + w + 1) * 128 + oc4) = pk;
        }
    }
}

// ---------------------------------------------------------------------------
// FUSED chain head, tl & br merged (round-9 proven). grid (4096)
// ---------------------------------------------------------------------------
__global__ __launch_bounds__(256, 4)
void conv3p1_k(const unsigned short* __restrict__ u0,    // tt; bb at +T128
               const unsigned short* __restrict__ xb,
               const unsigned short* __restrict__ w30,   // wp_tl3; wp_br3 at +294912
               const unsigned short* __restrict__ w10,   // wp_tl1; wp_br1 at +65536
               const float* __restrict__ bsum0,          // [0..255]=tl, [256..511]=br
               unsigned short* __restrict__ outTL,
               unsigned short* __restrict__ outBR)
{
    __shared__ unsigned short lds[2][8704];
    const int tid  = threadIdx.x;
    const int lane = tid & 63;
    const int wv   = tid >> 6;
    const int c    = lane & 15;
    const int g    = lane >> 4;

    const int b  = blockIdx.x;
    const int x  = b & 7;
    const int s  = b >> 3;
    const int q  = s & 1;
    const int gx = (s >> 1) & 3;
    const int sp = x + 8 * (s >> 3);
    const int hy = sp & 63;
    const int n  = sp >> 6;
    const int wtile  = gx & 1;
    const int octile = gx >> 1;
    const int h0 = hy * 2;
    const int w0 = wtile * 64;
    const int r  = wv >> 1;
    const int ocbase = octile * 128 + (wv & 1) * 64;
    const int ocf0   = octile * 8 + (wv & 1) * 4;

    const unsigned short* in3 = u0 + (size_t)q * ((size_t)8 * 130 * 130 * 128);
    const unsigned short* w3  = w30 + q * 294912;
    const unsigned short* w1  = w10 + q * 65536;
    const float* bi = bsum0 + q * 256;
    unsigned short* outv = q ? outBR : outTL;

    int addrB[3];
    #pragma unroll
    for (int kx = 0; kx < 3; ++kx) {
        int ps0 = c + kx;
        addrB[kx] = r * 4224 + ps0 * 64 + ((g ^ ((ps0 >> 1) & 3)) << 4);
    }
    const int addrC1 = r * 4096 + c * 64 + ((g ^ ((c >> 1) & 3)) << 4);

    int so3[5];
    #pragma unroll
    for (int it = 0; it < 5; ++it) {
        int u   = it * 256 + tid;
        int row = u / 264;
        int rem = u - row * 264;
        int ps  = rem >> 2;
        int ss  = rem & 3;
        int icq = ss ^ ((ps >> 1) & 3);
        so3[it] = ((n * 130 + h0 + row) * 130 + (w0 + ps)) * 128 + icq * 8;
    }
    int so1[4];
    #pragma unroll
    for (int it = 0; it < 4; ++it) {
        int u   = it * 256 + tid;
        int sub = u >> 9;
        int v   = u & 511;
        int row = v >> 8;
        int rem = v & 255;
        int px  = rem >> 2;
        int ss  = rem & 3;
        int icq = ss ^ ((px >> 1) & 3);
        so1[it] = ((n * 130 + h0 + 1 + row) * 130 + (w0 + px + 1)) * 256 + sub * 32 + icq * 8;
    }

    auto STAGE3 = [&](int chunk, int bsel) {
        const unsigned short* bp = in3 + chunk * 32;
        char* lb = (char*)lds + bsel * 17408 + tid * 16;
        #pragma unroll
        for (int it = 0; it < 4; ++it)
            GL_LDS(bp + so3[it], lb + it * 4096);
        if (wv == 0)
            GL_LDS(bp + so3[4], lb + 16384);
    };
    auto STAGE1 = [&](int j, int bsel) {
        const unsigned short* bp = xb + j * 64;
        char* lb = (char*)lds + bsel * 17408 + tid * 16;
        #pragma unroll
        for (int it = 0; it < 4; ++it)
            GL_LDS(bp + so1[it], lb + it * 4096);
    };

    f32x4 acc[4][4];
    #pragma unroll
    for (int m = 0; m < 4; ++m)
        #pragma unroll
        for (int p = 0; p < 4; ++p) acc[m][p] = 0.0f;

    STAGE3(0, 0);
    __syncthreads();

    for (int ph = 0; ph < 8; ++ph) {
        const int cur = ph & 1;
        if (ph < 3)      STAGE3(ph + 1, cur ^ 1);
        else if (ph < 7) STAGE1(ph - 3, cur ^ 1);
        const char* lb = (const char*)lds + cur * 17408;
        if (ph < 4) {
            #pragma unroll
            for (int kk = 0; kk < 9; ++kk) {
                const int ky = kk / 3, kx = kk % 3;
                s16x8 af[4], bf[4];
                #pragma unroll
                for (int m = 0; m < 4; ++m)
                    af[m] = *(const s16x8*)(w3
                        + ((size_t)((ph * 9 + kk) * 16 + ocf0 + m)) * 512 + lane * 8);
                #pragma unroll
                for (int p = 0; p < 4; ++p)
                    bf[p] = *(const s16x8*)(lb + addrB[kx] + ky * 4224 + p * 1024);
                #pragma unroll
                for (int m = 0; m < 4; ++m)
                    #pragma unroll
                    for (int p = 0; p < 4; ++p)
                        acc[m][p] = __builtin_amdgcn_mfma_f32_16x16x32_bf16(af[m], bf[p], acc[m][p], 0, 0, 0);
            }
        } else {
            const int j = ph - 4;
            #pragma unroll
            for (int sub = 0; sub < 2; ++sub) {
                s16x8 af[4], bf[4];
                #pragma unroll
                for (int m = 0; m < 4; ++m)
                    af[m] = *(const s16x8*)(w1
                        + ((size_t)(((j * 2 + sub) * 16) + ocf0 + m)) * 512 + lane * 8);
                #pragma unroll
                for (int p = 0; p < 4; ++p)
                    bf[p] = *(const s16x8*)(lb + sub * 8192 + addrC1 + p * 1024);
                #pragma unroll
                for (int m = 0; m < 4; ++m)
                    #pragma unroll
                    for (int p = 0; p < 4; ++p)
                        acc[m][p] = __builtin_amdgcn_mfma_f32_16x16x32_bf16(af[m], bf[p], acc[m][p], 0, 0, 0);
            }
        }
        __syncthreads();
    }

    #pragma unroll
    for (int m = 0; m < 4; ++m) {
        const int oc4 = ocbase + m * 16 + g * 4;
        const f4v b4 = *(const f4v*)(bi + oc4);
        #pragma unroll
        for (int p = 0; p < 4; ++p) {
            const int w = w0 + p * 16 + c;
            u16x4 pk;
            #pragma unroll
            for (int j = 0; j < 4; ++j)
                pk[j] = f2bf(fmaxf(acc[m][p][j] + b4[j], 0.0f));
            *(u16x4*)(outv + ((size_t)(n * 130 + h0 + r + 1) * 130 + w + 1) * 256 + oc4) = pk;
        }
    }
}

// ---------------------------------------------------------------------------
__global__ __launch_bounds__(128)
void pool_h2_k(unsigned short* __restrict__ ta, unsigned short* __restrict__ tb)
{
    const int sel = blockIdx.x & 1;
    const int col = blockIdx.x >> 1;
    unsigned short* p = sel ? tb : ta;
    const int n = col >> 7, w = col & 127, cth = threadIdx.x;
    unsigned short* base = p + (((size_t)n * 130 + 1) * 130 + (w + 1)) * 128 + cth;
    const int stride = 130 * 128;
    float m = -3.402823466e+38f;
    if (sel == 0) {
        for (int gq = 0; gq < 16; ++gq) {
            const int h0 = 127 - gq * 8;
            float v[8];
            #pragma unroll
            for (int j = 0; j < 8; ++j) v[j] = bf2f(base[(size_t)(h0 - j) * stride]);
            unsigned short o[8];
            #pragma unroll
            for (int j = 0; j < 8; ++j) { m = fmaxf(m, v[j]); o[j] = f2bf(m); }
            #pragma unroll
            for (int j = 0; j < 8; ++j) base[(size_t)(h0 - j) * stride] = o[j];
        }
    } else {
        for (int gq = 0; gq < 16; ++gq) {
            const int h0 = gq * 8;
            float v[8];
            #pragma unroll
            for (int j = 0; j < 8; ++j) v[j] = bf2f(base[(size_t)(h0 + j) * stride]);
            unsigned short o[8];
            #pragma unroll
            for (int j = 0; j < 8; ++j) { m = fmaxf(m, v[j]); o[j] = f2bf(m); }
            #pragma unroll
            for (int j = 0; j < 8; ++j) base[(size_t)(h0 + j) * stride] = o[j];
        }
    }
}

__global__ __launch_bounds__(128)
void pool_w_add2_k(const unsigned short* __restrict__ la, unsigned short* __restrict__ ta,
                   const unsigned short* __restrict__ lb, unsigned short* __restrict__ tb)
{
    const int sel = blockIdx.x & 1;
    const int row = blockIdx.x >> 1;
    const unsigned short* ls = sel ? lb : la;
    unsigned short* td = sel ? tb : ta;
    const int n = row >> 7, hh = row & 127, cth = threadIdx.x;
    const size_t rowbase = ((size_t)(n * 130 + hh + 1) * 130) * 128 + cth;
    float m = -3.402823466e+38f;
    if (sel == 0) {
        for (int gq = 0; gq < 16; ++gq) {
            const int w0 = 127 - gq * 8;
            float lv[8], tv[8];
            #pragma unroll
            for (int j = 0; j < 8; ++j) {
                size_t off = rowbase + (size_t)(w0 - j + 1) * 128;
                lv[j] = bf2f(ls[off]); tv[j] = bf2f(td[off]);
            }
            unsigned short o[8];
            #pragma unroll
            for (int j = 0; j < 8; ++j) { m = fmaxf(m, lv[j]); o[j] = f2bf(m + tv[j]); }
            #pragma unroll
            for (int j = 0; j < 8; ++j) td[rowbase + (size_t)(w0 - j + 1) * 128] = o[j];
        }
    } else {
        for (int gq = 0; gq < 16; ++gq) {
            const int w0 = gq * 8;
            float lv[8], tv[8];
            #pragma unroll
            for (int j = 0; j < 8; ++j) {
                size_t off = rowbase + (size_t)(w0 + j + 1) * 128;
                lv[j] = bf2f(ls[off]); tv[j] = bf2f(td[off]);
            }
            unsigned short o[8];
            #pragma unroll
            for (int j = 0; j < 8; ++j) { m = fmaxf(m, lv[j]); o[j] = f2bf(m + tv[j]); }
            #pragma unroll
            for (int j = 0; j < 8; ++j) td[rowbase + (size_t)(w0 + j + 1) * 128] = o[j];
        }
    }
}

// ---------------------------------------------------------------------------
__global__ __launch_bounds__(256)
void padzero_k(unsigned short* __restrict__ t, int C)
{
    int idx = blockIdx.x * 256 + threadIdx.x;
    int n = blockIdx.y;
    int cpu = C >> 3;
    if (idx >= 516 * cpu) return;
    int cell = idx / cpu, cq = idx - cell * cpu;
    int h, w;
    if (cell < 260) { h = (cell < 130) ? -1 : 128; w = (cell % 130) - 1; }
    else { int j = cell - 260; w = (j < 128) ? -1 : 128; h = j & 127; }
    size_t off = (((size_t)n * 130 + h + 1) * 130 + (w + 1)) * C + cq * 8;
    uint4 z; z.x = 0; z.y = 0; z.z = 0; z.w = 0;
    *(uint4*)(t + off) = z;
}

__global__ __launch_bounds__(256)
void padzero_all_k(unsigned short* xb, unsigned short* tt, unsigned short* bb,
                   unsigned short* ll, unsigned short* rr, unsigned short* pbr)
{
    const int id = blockIdx.y;
    unsigned short* t = id == 0 ? xb : (id == 1 ? tt : (id == 2 ? bb :
                        (id == 3 ? ll : (id == 4 ? rr : pbr))));
    const int C = (id == 0 || id == 5) ? 256 : 128;
    int idx = blockIdx.x * 256 + threadIdx.x;
    int n = blockIdx.z;
    int cpu = C >> 3;
    if (idx >= 516 * cpu) return;
    int cell = idx / cpu, cq = idx - cell * cpu;
    int h, w;
    if (cell < 260) { h = (cell < 130) ? -1 : 128; w = (cell % 130) - 1; }
    else { int j = cell - 260; w = (j < 128) ? -1 : 128; h = j & 127; }
    size_t off = (((size_t)n * 130 + h + 1) * 130 + (w + 1)) * C + cq * 8;
    uint4 z; z.x = 0; z.y = 0; z.z = 0; z.w = 0;
    *(uint4*)(t + off) = z;
}

// ---------------------------------------------------------------------------
__global__ __launch_bounds__(256)
void transform_x_k(const float* __restrict__ x, unsigned short* __restrict__ xb)
{
    __shared__ float sm[64][132];
    const int h = blockIdx.x, n = blockIdx.y, t = threadIdx.x;
    for (int cc0 = 0; cc0 < 256; cc0 += 64) {
        __syncthreads();
        {
            int ci = t >> 7, wi = t & 127;
            #pragma unroll 8
            for (int k = 0; k < 32; ++k)
                sm[ci + 2 * k][wi] = x[((size_t)(n * 256 + cc0 + ci + 2 * k) << 14) + (h << 7) + wi];
        }
        __syncthreads();
        {
            int wi = t >> 1, cq = t & 1;
            unsigned short tmp[32];
            #pragma unroll
            for (int m2 = 0; m2 < 32; ++m2) tmp[m2] = f2bf(sm[cq * 32 + m2][wi]);
            unsigned short* dst = xb + (((size_t)n * 130 + h + 1) * 130 + wi + 1) * 256 + cc0 + cq * 32;
            #pragma unroll
            for (int q = 0; q < 4; ++q) *(uint4*)(dst + q * 8) = *(const uint4*)(tmp + q * 8);
        }
    }
}

// ---------------------------------------------------------------------------
struct PrepArgs {
    const float* w[10];          // t,l,b,r,tl3,br3,tlo,bro,tl1,br1
    unsigned short* dst[10];
    const float* s[10];
    const float* bv[4];
    const float* bx[4];          // b_tl3,b_tl1,b_br3,b_br1
    float* bA; float* bsum;
};

__global__ __launch_bounds__(256)
void prepack_all_k(PrepArgs a)
{
    const int id = blockIdx.y;
    int idx = blockIdx.x * 256 + threadIdx.x;
    if (id == 10) {
        if (idx < 512) a.bA[idx] = a.bv[idx >> 7][idx & 127];
        else if (idx < 768)  { int i = idx - 512; a.bsum[i]       = a.bx[0][i] + a.bx[1][i]; }
        else if (idx < 1024) { int i = idx - 768; a.bsum[256 + i] = a.bx[2][i] + a.bx[3][i]; }
        return;
    }
    if (id >= 8) {
        if (idx >= 65536) return;
        int ic = idx & 255, oc = idx >> 8;
        float v = a.w[id][oc * 256 + ic] * a.s[id][oc];
        int chunk = ic >> 5, icr = ic & 31, gg = icr >> 3, j = icr & 7;
        int m = oc >> 4, ocr = oc & 15, ln = gg * 16 + ocr;
        a.dst[id][((size_t)(chunk * 16 + m)) * 512 + ln * 8 + j] = f2bf(v);
        return;
    }
    const int CIN  = (id < 4) ? 256 : ((id < 6) ? 128 : 256);
    const int COUT = (id < 4) ? 128 : 256;
    if (idx >= COUT * CIN * 9) return;
    int kk = idx % 9; int rest = idx / 9;
    int ic = rest % CIN; int oc = rest / CIN;
    float v = a.w[id][(size_t)(oc * CIN + ic) * 9 + kk] * a.s[id][oc];
    int chunk = ic >> 5, icr = ic & 31, gg = icr >> 3, j = icr & 7;
    int m = oc >> 4, ocr = oc & 15, ln = gg * 16 + ocr;
    a.dst[id][((size_t)((chunk * 9 + kk) * (COUT / 16) + m)) * 512 + ln * 8 + j] = f2bf(v);
}

// ---------------------------------------------------------------------------
extern "C" void kernel_launch(void* const* d_in, const int* in_sizes, int n_in,
                              void* d_out, int out_size, void* d_ws, size_t ws_size,
                              hipStream_t stream)
{
    const float* x     = (const float*)d_in[0];
    const float* w_t   = (const float*)d_in[1];
    const float* s_t   = (const float*)d_in[2];
    const float* b_t   = (const float*)d_in[3];
    const float* w_l   = (const float*)d_in[4];
    const float* s_l   = (const float*)d_in[5];
    const float* b_l   = (const float*)d_in[6];
    const float* w_b   = (const float*)d_in[7];
    const float* s_b   = (const float*)d_in[8];
    const float* b_b   = (const float*)d_in[9];
    const float* w_r   = (const float*)d_in[10];
    const float* s_r   = (const float*)d_in[11];
    const float* b_r   = (const float*)d_in[12];
    const float* w_tl3 = (const float*)d_in[13];
    const float* s_tl3 = (const float*)d_in[14];
    const float* b_tl3 = (const float*)d_in[15];
    const float* w_br3 = (const float*)d_in[16];
    const float* s_br3 = (const float*)d_in[17];
    const float* b_br3 = (const float*)d_in[18];
    const float* w_tl1 = (const float*)d_in[19];
    const float* s_tl1 = (const float*)d_in[20];
    const float* b_tl1 = (const float*)d_in[21];
    const float* w_br1 = (const float*)d_in[22];
    const float* s_br1 = (const float*)d_in[23];
    const float* b_br1 = (const float*)d_in[24];
    const float* w_tlo = (const float*)d_in[25];
    const float* s_tlo = (const float*)d_in[26];
    const float* b_tlo = (const float*)d_in[27];
    const float* w_bro = (const float*)d_in[28];
    const float* s_bro = (const float*)d_in[29];
    const float* b_bro = (const float*)d_in[30];

    typedef unsigned short ush;
    const size_t T256 = (size_t)8 * 130 * 130 * 256;
    const size_t T128 = (size_t)8 * 130 * 130 * 128;

    ush* xb = (ush*)d_ws;
    ush* tt = xb + T256;
    ush* bb = tt + T128;
    ush* ll = bb + T128;
    ush* rr = ll + T128;
    ush* wq = rr + T128;
    ush* wp_t   = wq;                    // stage-A 4x 294912 contiguous
    ush* wp_l   = wp_t   + 294912;
    ush* wp_b   = wp_l   + 294912;
    ush* wp_r   = wp_b   + 294912;
    ush* wp_tl3 = wp_r   + 294912;       // tl3, br3 contiguous
    ush* wp_br3 = wp_tl3 + 294912;
    ush* wp_tlo = wp_br3 + 294912;       // tlo, bro contiguous
    ush* wp_bro = wp_tlo + 589824;
    ush* wp_tl1 = wp_bro + 589824;       // tl1, br1 contiguous
    ush* wp_br1 = wp_tl1 + 65536;
    float* bA   = (float*)(wp_br1 + 65536);  // 512 f
    float* bsum = bA + 512;                  // 512 f
    ush* tl  = ll;                           // 256-ch buffer over ll+rr
    ush* pbr = (ush*)d_out;                  // P_br staging in d_out 1st half

    PrepArgs pa;
    pa.w[0] = w_t;  pa.w[1] = w_l;  pa.w[2] = w_b;  pa.w[3] = w_r;
    pa.w[4] = w_tl3; pa.w[5] = w_br3; pa.w[6] = w_tlo; pa.w[7] = w_bro;
    pa.w[8] = w_tl1; pa.w[9] = w_br1;
    pa.dst[0] = wp_t;  pa.dst[1] = wp_l;  pa.dst[2] = wp_b;  pa.dst[3] = wp_r;
    pa.dst[4] = wp_tl3; pa.dst[5] = wp_br3; pa.dst[6] = wp_tlo; pa.dst[7] = wp_bro;
    pa.dst[8] = wp_tl1; pa.dst[9] = wp_br1;
    pa.s[0] = s_t;  pa.s[1] = s_l;  pa.s[2] = s_b;  pa.s[3] = s_r;
    pa.s[4] = s_tl3; pa.s[5] = s_br3; pa.s[6] = s_tlo; pa.s[7] = s_bro;
    pa.s[8] = s_tl1; pa.s[9] = s_br1;
    pa.bv[0] = b_t; pa.bv[1] = b_l; pa.bv[2] = b_b; pa.bv[3] = b_r;
    pa.bx[0] = b_tl3; pa.bx[1] = b_tl1; pa.bx[2] = b_br3; pa.bx[3] = b_br1;
    pa.bA = bA; pa.bsum = bsum;
    prepack_all_k<<<dim3(2304, 11), dim3(256), 0, stream>>>(pa);
    padzero_all_k<<<dim3(516, 6, 8), dim3(256), 0, stream>>>(xb, tt, bb, ll, rr, pbr);
    transform_x_k<<<dim3(128, 8), dim3(256), 0, stream>>>(x, xb);

    // stage A: t,l,b,r merged, XCD-tile-grouped
    conv3_tlbr<<<dim3(4096), dim3(256), 0, stream>>>(xb, wp_t, bA, tt);

    // pools: u1 = revcummaxH(tt)+revcummaxW(ll); u2 = cummaxH(bb)+cummaxW(rr)
    pool_h2_k<<<dim3(2048), dim3(128), 0, stream>>>(tt, bb);
    pool_w_add2_k<<<dim3(2048), dim3(128), 0, stream>>>(ll, tt, rr, bb);

    // fused chain heads: tl -> tl buffer, br -> d_out 1st half (P_br)
    padzero_k<<<dim3(66, 8), dim3(256), 0, stream>>>(tl, 256);
    conv3p1_k<<<dim3(4096), dim3(256), 0, stream>>>(tt, xb, wp_tl3, wp_tl1, bsum, tl, pbr);

    // serialized finals (round-9 proven): bro reads P_br (d_out 1st half) and
    // writes 2nd half; then tlo overwrites 1st half.
    conv3_mfma<256, 256, true, true, true><<<dim3(4, 64, 8), dim3(256), 0, stream>>>(
        pbr, wp_bro, b_bro, (float*)d_out + 33554432);
    conv3_mfma<256, 256, true, true, true><<<dim3(4, 64, 8), dim3(256), 0, stream>>>(
        tl, wp_tlo, b_tlo, d_out);
}